// Round 12
// baseline (754.674 us; speedup 1.0000x reference)
//
#include <hip/hip_runtime.h>
#include <hip/hip_bf16.h>

#define BATCH 32
#define NPOS 784
#define DIM 768
#define HEADS 12
#define HD 64
#define AGENT 49
#define HH 28
#define WW 28
#define MROWS (BATCH*NPOS)   // 25088
#define SCALE 0.125f

using bf16 = __hip_bfloat16;
typedef __attribute__((ext_vector_type(4))) float f32x4;
typedef __attribute__((ext_vector_type(8))) short short8v;

__device__ __forceinline__ float bf2f(bf16 x) { return __bfloat162float(x); }
__device__ __forceinline__ float bfs2f(short s) {
    unsigned int u = ((unsigned int)(unsigned short)s) << 16;
    return __uint_as_float(u);
}
__device__ __forceinline__ unsigned short f2bf(float x) {
    unsigned int u = __float_as_uint(x);
    unsigned int r = (u + 0x7fffu + ((u >> 16) & 1u)) >> 16;
    return (unsigned short)r;
}

// async global->LDS, 16B per lane (dest must be wave-uniform base + lane*16)
#define GLOAD_LDS16(g, l) __builtin_amdgcn_global_load_lds( \
    (const __attribute__((address_space(1))) unsigned int*)(g), \
    (__attribute__((address_space(3))) unsigned int*)(l), 16, 0, 0)

// ---------------------------------------------------------------------------
// f32 -> bf16 convert (vectorized): dst[i] = bf16(src[i]), n8 = n/8
// ---------------------------------------------------------------------------
__global__ __launch_bounds__(256) void convert_bf16(
    const float* __restrict__ src, bf16* __restrict__ dst, int n8)
{
    int idx = blockIdx.x * 256 + threadIdx.x;
    if (idx >= n8) return;
    const float* p = src + (size_t)idx * 8;
    float4 r0 = *reinterpret_cast<const float4*>(p);
    float4 r1 = *reinterpret_cast<const float4*>(p + 4);
    short8v v;
    v[0] = (short)f2bf(r0.x); v[1] = (short)f2bf(r0.y);
    v[2] = (short)f2bf(r0.z); v[3] = (short)f2bf(r0.w);
    v[4] = (short)f2bf(r1.x); v[5] = (short)f2bf(r1.y);
    v[6] = (short)f2bf(r1.z); v[7] = (short)f2bf(r1.w);
    *reinterpret_cast<short8v*>((short*)dst + (size_t)idx * 8) = v;
}

// ---------------------------------------------------------------------------
// Transpose+convert: W [K][N] f32 -> Wt [N][K] bf16. 256 thr = 32x8.
// ---------------------------------------------------------------------------
__global__ __launch_bounds__(256) void transpose_w_bf16(
    const float* __restrict__ W, bf16* __restrict__ Wt, int K, int N)
{
    __shared__ float t[32][33];
    int tx = threadIdx.x & 31, ty = threadIdx.x >> 5;
    int k0 = blockIdx.y * 32, n0 = blockIdx.x * 32;
#pragma unroll
    for (int i = 0; i < 4; ++i)
        t[ty + 8 * i][tx] = W[(size_t)(k0 + ty + 8 * i) * N + n0 + tx];
    __syncthreads();
#pragma unroll
    for (int i = 0; i < 4; ++i)
        Wt[(size_t)(n0 + ty + 8 * i) * K + k0 + tx] = __float2bfloat16(t[tx][ty + 8 * i]);
}

// ---------------------------------------------------------------------------
// MFMA GEMM, 2-phase double-buffered (T3-minimum): C = A @ Bt^T, f32 accum.
// 128x128 tile, BK=64, global_load_lds w16 both operands, XOR-swizzled LDS,
// bijective XCD grid swizzle. K-loop: issue stage(t+1) -> compute(t) ->
// vmcnt(0) -> raw s_barrier (ONE barrier/K-step; HBM latency hides under
// MFMA). LDS 64 KB (2 buf) -> still 2 blocks/CU.
// ---------------------------------------------------------------------------
template<bool OUTF32>
__global__ __launch_bounds__(256) void gemm_mfma(
    const bf16* __restrict__ A, const bf16* __restrict__ Bt,
    const float* __restrict__ bias, void* __restrict__ Cp,
    int M, int N, int K)
{
    __shared__ __align__(16) short As[2][128 * 64];
    __shared__ __align__(16) short Bs[2][128 * 64];

    int tid = threadIdx.x;
    int wave = tid >> 6, lane = tid & 63;

    // bijective XCD swizzle: contiguous chunk of blocks per XCD
    int gx = gridDim.x;
    int nwg = gx * gridDim.y;
    int bid = blockIdx.y * gx + blockIdx.x;
    int cpx = nwg >> 3;
    int nb = (bid & 7) * cpx + (bid >> 3);
    int m0 = (nb / gx) * 128, n0 = (nb % gx) * 128;

    int wm = (wave >> 1) * 64, wn = (wave & 1) * 64;
    int acol = lane & 15, kgrp = lane >> 4;

    f32x4 acc[4][4] = {};
    const short* Ab = (const short*)A;
    const short* Btb = (const short*)Bt;

    // staging: 1024 16B chunks per operand, pre-swizzled source
    auto STAGE = [&](int buf, int k0) {
#pragma unroll
        for (int it = 0; it < 4; ++it) {
            int idx = tid + 256 * it;
            int row = idx >> 3, seg = idx & 7;
            int sseg = seg ^ (row & 7);
            GLOAD_LDS16(Ab + (size_t)(m0 + row) * K + k0 + sseg * 8, &As[buf][idx * 8]);
        }
#pragma unroll
        for (int it = 0; it < 4; ++it) {
            int idx = tid + 256 * it;
            int row = idx >> 3, seg = idx & 7;
            int sseg = seg ^ (row & 7);
            GLOAD_LDS16(Btb + (size_t)(n0 + row) * K + k0 + sseg * 8, &Bs[buf][idx * 8]);
        }
    };

    int nt = K >> 6;        // K-steps of 64
    int cur = 0;

    // prologue: stage tile 0, wait, barrier
    STAGE(0, 0);
    asm volatile("s_waitcnt vmcnt(0)" ::: "memory");
    __builtin_amdgcn_sched_barrier(0);
    __builtin_amdgcn_s_barrier();
    __builtin_amdgcn_sched_barrier(0);

    for (int t = 0; t < nt; ++t) {
        if (t + 1 < nt) STAGE(cur ^ 1, (t + 1) << 6);   // issue next tile

        // compute current tile (compiler inserts lgkm waits for ds_reads)
#pragma unroll
        for (int kk = 0; kk < 2; ++kk) {
            short8v af[4], bfr[4];
#pragma unroll
            for (int mf = 0; mf < 4; ++mf) {
                int row = wm + mf * 16 + acol;
                int seg = (kk * 4 + kgrp) ^ (row & 7);
                af[mf] = *reinterpret_cast<const short8v*>(&As[cur][row * 64 + seg * 8]);
            }
#pragma unroll
            for (int nf = 0; nf < 4; ++nf) {
                int row = wn + nf * 16 + acol;
                int seg = (kk * 4 + kgrp) ^ (row & 7);
                bfr[nf] = *reinterpret_cast<const short8v*>(&Bs[cur][row * 64 + seg * 8]);
            }
#pragma unroll
            for (int mf = 0; mf < 4; ++mf)
#pragma unroll
                for (int nf = 0; nf < 4; ++nf)
                    acc[mf][nf] = __builtin_amdgcn_mfma_f32_16x16x32_bf16(
                        af[mf], bfr[nf], acc[mf][nf], 0, 0, 0);
        }

        if (t + 1 < nt) {
            // drain next-tile stage (latency hidden under the MFMAs above),
            // then one barrier: all waves' reads of buf[cur] done, all
            // staging of buf[cur^1] landed.
            asm volatile("s_waitcnt vmcnt(0)" ::: "memory");
            __builtin_amdgcn_sched_barrier(0);
            __builtin_amdgcn_s_barrier();
            __builtin_amdgcn_sched_barrier(0);
            cur ^= 1;
        }
    }

    int rgrp = kgrp * 4, cidx = acol;
#pragma unroll
    for (int mf = 0; mf < 4; ++mf)
#pragma unroll
        for (int nf = 0; nf < 4; ++nf)
#pragma unroll
            for (int r = 0; r < 4; ++r) {
                int row = m0 + wm + mf * 16 + rgrp + r;
                int col = n0 + wn + nf * 16 + cidx;
                float v = acc[mf][nf][r];
                if constexpr (OUTF32)
                    ((float*)Cp)[(size_t)row * N + col] = v + bias[col];
                else
                    ((bf16*)Cp)[(size_t)row * N + col] = __float2bfloat16(v);
            }
}

// ---------------------------------------------------------------------------
// Pool: ahp[b][a][c] = mean over 4x4 block of q[b][n][c]  (bf16 in, f32 out)
// ---------------------------------------------------------------------------
__global__ void pool_kernel(const bf16* __restrict__ q, float* __restrict__ ahp)
{
    int idx = blockIdx.x * 256 + threadIdx.x;
    if (idx >= BATCH * AGENT * DIM) return;
    int c = idx % DIM;
    int a = (idx / DIM) % AGENT;
    int b = idx / (DIM * AGENT);
    int ai = a / 7, aj = a % 7;
    float s = 0.f;
#pragma unroll
    for (int u = 0; u < 4; ++u)
#pragma unroll
        for (int v = 0; v < 4; ++v) {
            int n = (ai * 4 + u) * WW + (aj * 4 + v);
            s += bf2f(q[((size_t)b * NPOS + n) * DIM + c]);
        }
    ahp[idx] = s * (1.f / 16.f);
}

// ---------------------------------------------------------------------------
// Bilinear 7->28 upsample, half-pixel centers, edge clamp
// ---------------------------------------------------------------------------
__device__ __forceinline__ float bilerp7(const float* __restrict__ img, int i, int j)
{
    float si = 0.25f * i - 0.375f, sj = 0.25f * j - 0.375f;
    int i0 = (int)floorf(si); float fi = si - i0;
    int j0 = (int)floorf(sj); float fj = sj - j0;
    int i0c = min(max(i0, 0), 6), i1c = min(max(i0 + 1, 0), 6);
    int j0c = min(max(j0, 0), 6), j1c = min(max(j0 + 1, 0), 6);
    float v00 = img[i0c * 7 + j0c], v01 = img[i0c * 7 + j1c];
    float v10 = img[i1c * 7 + j0c], v11 = img[i1c * 7 + j1c];
    return (1.f - fi) * ((1.f - fj) * v00 + fj * v01) + fi * ((1.f - fj) * v10 + fj * v11);
}

__global__ void pos_bias_kernel(const float* __restrict__ an, const float* __restrict__ ah_b,
                                const float* __restrict__ aw_b, bf16* __restrict__ pb)
{
    int idx = blockIdx.x * 256 + threadIdx.x;
    if (idx >= HEADS * AGENT * NPOS) return;
    int n = idx % NPOS;
    int a = (idx / NPOS) % AGENT;
    int h = idx / (NPOS * AGENT);
    int i = n / WW, j = n % WW;
    float v = bilerp7(an + (size_t)(h * AGENT + a) * 49, i, j);
    v += ah_b[(h * AGENT + a) * HH + i] + aw_b[(h * AGENT + a) * WW + j];
    pb[idx] = __float2bfloat16(v);
}

__global__ void ag_bias_kernel(const float* __restrict__ na, const float* __restrict__ ha_b,
                               const float* __restrict__ wa_b, bf16* __restrict__ ab)
{
    int idx = blockIdx.x * 256 + threadIdx.x;
    if (idx >= HEADS * NPOS * AGENT) return;
    int a = idx % AGENT;
    int n = (idx / AGENT) % NPOS;
    int h = idx / (AGENT * NPOS);
    int i = n / WW, j = n % WW;
    float v = bilerp7(na + (size_t)(h * AGENT + a) * 49, i, j);
    v += ha_b[(h * HH + i) * AGENT + a] + wa_b[(h * WW + j) * AGENT + a];
    ab[idx] = __float2bfloat16(v);
}

// ---------------------------------------------------------------------------
// Agent attention v3 (full MFMA): one block per (b,h), 4 waves. (unchanged)
// ---------------------------------------------------------------------------
__global__ __launch_bounds__(256, 2) void agent_attn3(
    const float* __restrict__ ahp, const bf16* __restrict__ kv,
    const bf16* __restrict__ pb, bf16* __restrict__ agent_v)
{
    __shared__ __align__(16) char smem[75776];
    short (*pL)[64][72]  = (short (*)[64][72])smem;            // [4][64][72]
    short (*VtL)[64][72] = (short (*)[64][72])(smem + 36864);  // [4][64][72]
    float (*Om)[64][66]  = (float (*)[64][66])smem;            // aliases pL/VtL
    float (*mw)[64]      = (float (*)[64])(smem + 73728);
    float (*lw)[64]      = (float (*)[64])(smem + 74752);

    int tid = threadIdx.x;
    int wave = tid >> 6, lane = tid & 63;
    int acol = lane & 15, kgrp = lane >> 4;
    int h = blockIdx.x % HEADS;
    int b = blockIdx.x / HEADS;
    const short* kvs = (const short*)kv;
    const bf16* pbh = pb + (size_t)h * AGENT * NPOS;

    short8v qa[2][4];
#pragma unroll
    for (int ks = 0; ks < 2; ++ks)
#pragma unroll
        for (int mf = 0; mf < 4; ++mf) {
            int a = mf * 16 + acol;
            short8v v = {};
            if (a < AGENT) {
                const float* src = ahp + ((size_t)b * AGENT + a) * DIM + h * HD + ks * 32 + kgrp * 8;
                float4 r0 = *reinterpret_cast<const float4*>(src);
                float4 r1 = *reinterpret_cast<const float4*>(src + 4);
                v[0] = (short)f2bf(r0.x * SCALE); v[1] = (short)f2bf(r0.y * SCALE);
                v[2] = (short)f2bf(r0.z * SCALE); v[3] = (short)f2bf(r0.w * SCALE);
                v[4] = (short)f2bf(r1.x * SCALE); v[5] = (short)f2bf(r1.y * SCALE);
                v[6] = (short)f2bf(r1.z * SCALE); v[7] = (short)f2bf(r1.w * SCALE);
            }
            qa[ks][mf] = v;
        }

    float mrun[16], lrun[16];
#pragma unroll
    for (int i = 0; i < 16; ++i) { mrun[i] = -1e30f; lrun[i] = 0.f; }
    f32x4 accO[4][4] = {};

    for (int t = wave; t < 13; t += 4) {
        int n0 = t * 64;
        {
            int p = lane & 31, dh = lane >> 5;
            const short* v0p = kvs + (size_t)(b * NPOS + n0 + 2 * p) * (2 * DIM) + DIM + h * HD + dh * 32;
#pragma unroll
            for (int s = 0; s < 4; ++s) {
                short8v va = {}, vb = {};
                if (n0 + 2 * p < NPOS)     va = *reinterpret_cast<const short8v*>(v0p + s * 8);
                if (n0 + 2 * p + 1 < NPOS) vb = *reinterpret_cast<const short8v*>(v0p + 2 * DIM + s * 8);
#pragma unroll
                for (int u = 0; u < 8; ++u) {
                    int d = dh * 32 + s * 8 + u;
                    unsigned int w = ((unsigned int)(unsigned short)va[u]) |
                                     (((unsigned int)(unsigned short)vb[u]) << 16);
                    *reinterpret_cast<unsigned int*>(&VtL[wave][d][2 * p]) = w;
                }
            }
        }

        short8v kb[2][4];
#pragma unroll
        for (int nf = 0; nf < 4; ++nf) {
            int n = n0 + nf * 16 + acol;
            bool val = (n < NPOS);
            const short* kp = kvs + (size_t)(b * NPOS + n) * (2 * DIM) + h * HD + kgrp * 8;
#pragma unroll
            for (int ks = 0; ks < 2; ++ks) {
                short8v v = {};
                if (val) v = *reinterpret_cast<const short8v*>(kp + ks * 32);
                kb[ks][nf] = v;
            }
        }

        f32x4 accS[4][4] = {};
#pragma unroll
        for (int mf = 0; mf < 4; ++mf)
#pragma unroll
            for (int nf = 0; nf < 4; ++nf) {
                accS[mf][nf] = __builtin_amdgcn_mfma_f32_16x16x32_bf16(qa[0][mf], kb[0][nf], accS[mf][nf], 0, 0, 0);
                accS[mf][nf] = __builtin_amdgcn_mfma_f32_16x16x32_bf16(qa[1][mf], kb[1][nf], accS[mf][nf], 0, 0, 0);
            }

#pragma unroll
        for (int mf = 0; mf < 4; ++mf)
#pragma unroll
            for (int r = 0; r < 4; ++r) {
                int a = mf * 16 + kgrp * 4 + r;
                float s[4];
                float mt = -1e30f;
#pragma unroll
                for (int nf = 0; nf < 4; ++nf) {
                    int n = n0 + nf * 16 + acol;
                    float sv = -1e30f;
                    if (n < NPOS) {
                        sv = accS[mf][nf][r];
                        if (a < AGENT) sv += bf2f(pbh[(size_t)a * NPOS + n]);
                    }
                    s[nf] = sv;
                    mt = fmaxf(mt, sv);
                }
#pragma unroll
                for (int off = 1; off < 16; off <<= 1)
                    mt = fmaxf(mt, __shfl_xor(mt, off));
                float mnew = fmaxf(mrun[mf * 4 + r], mt);
                float fac = __expf(mrun[mf * 4 + r] - mnew);
                float ps = 0.f;
#pragma unroll
                for (int nf = 0; nf < 4; ++nf) {
                    float pv = (s[nf] > -1e29f) ? __expf(s[nf] - mnew) : 0.f;
                    ps += pv;
                    pL[wave][a][nf * 16 + acol] = (short)f2bf(pv);
                }
#pragma unroll
                for (int off = 1; off < 16; off <<= 1)
                    ps += __shfl_xor(ps, off);
                mrun[mf * 4 + r] = mnew;
                lrun[mf * 4 + r] = lrun[mf * 4 + r] * fac + ps;
#pragma unroll
                for (int df = 0; df < 4; ++df) accO[mf][df][r] *= fac;
            }

        short8v vb2[2][4];
#pragma unroll
        for (int ks = 0; ks < 2; ++ks)
#pragma unroll
            for (int df = 0; df < 4; ++df)
                vb2[ks][df] = *reinterpret_cast<const short8v*>(
                    &VtL[wave][df * 16 + acol][ks * 32 + kgrp * 8]);
#pragma unroll
        for (int mf = 0; mf < 4; ++mf) {
#pragma unroll
            for (int ks = 0; ks < 2; ++ks) {
                short8v pa = *reinterpret_cast<const short8v*>(
                    &pL[wave][mf * 16 + acol][ks * 32 + kgrp * 8]);
#pragma unroll
                for (int df = 0; df < 4; ++df)
                    accO[mf][df] = __builtin_amdgcn_mfma_f32_16x16x32_bf16(pa, vb2[ks][df], accO[mf][df], 0, 0, 0);
            }
        }
    }

    if (acol == 0) {
#pragma unroll
        for (int mf = 0; mf < 4; ++mf)
#pragma unroll
            for (int r = 0; r < 4; ++r) {
                mw[wave][mf * 16 + kgrp * 4 + r] = mrun[mf * 4 + r];
                lw[wave][mf * 16 + kgrp * 4 + r] = lrun[mf * 4 + r];
            }
    }
    __syncthreads();
#pragma unroll
    for (int mf = 0; mf < 4; ++mf)
#pragma unroll
        for (int df = 0; df < 4; ++df)
#pragma unroll
            for (int r = 0; r < 4; ++r)
                Om[wave][mf * 16 + kgrp * 4 + r][df * 16 + acol] = accO[mf][df][r];
    __syncthreads();

    for (int idx = tid; idx < AGENT * HD; idx += 256) {
        int a = idx >> 6, d = idx & 63;
        float m = fmaxf(fmaxf(mw[0][a], mw[1][a]), fmaxf(mw[2][a], mw[3][a]));
        float l = 0.f, o = 0.f;
#pragma unroll
        for (int w = 0; w < 4; ++w) {
            float f = __expf(mw[w][a] - m);
            l += f * lw[w][a];
            o += f * Om[w][a][d];
        }
        ((short*)agent_v)[(((size_t)b * HEADS + h) * AGENT + a) * HD + d] = (short)f2bf(o / l);
    }
}

// ---------------------------------------------------------------------------
// Q attention via MFMA + fused depthwise conv (vectorized), IN-PLACE over q.
// ---------------------------------------------------------------------------
__global__ __launch_bounds__(256) void q_attn_mfma(
    bf16* qpre, const bf16* __restrict__ kv_own,
    const float* __restrict__ ahp_x, const bf16* __restrict__ ab_x,
    const bf16* __restrict__ agv_x,
    const float* __restrict__ dwc_w, const float* __restrict__ dwc_b)
{
    __shared__ short pL[4][16][72];
    __shared__ float oL[4][16][68];
    __shared__ float wS[9][64];
    __shared__ float cbS[64];

    int blk = blockIdx.x;
    int half = blk & 1;
    int h = (blk >> 1) % HEADS;
    int b = blk / (2 * HEADS);
    int tid = threadIdx.x;
    int wave = tid >> 6, lane = tid & 63;
    int acol = lane & 15, kgrp = lane >> 4;

    for (int i = tid; i < 9 * 64; i += 256)
        wS[i >> 6][i & 63] = dwc_w[(i >> 6) * DIM + h * HD + (i & 63)];
    if (tid < 64) cbS[tid] = dwc_b[h * HD + tid];
    for (int i = tid; i < 4 * 16 * 72; i += 256)
        ((short*)pL)[i] = 0;

    short8v bs[2][4];
#pragma unroll
    for (int ks = 0; ks < 2; ++ks)
#pragma unroll
        for (int nf = 0; nf < 4; ++nf) {
            int a = nf * 16 + acol;
            short8v v = {};
            if (a < AGENT) {
                const float* src = ahp_x + ((size_t)b * AGENT + a) * DIM + h * HD + ks * 32 + kgrp * 8;
                float4 r0 = *reinterpret_cast<const float4*>(src);
                float4 r1 = *reinterpret_cast<const float4*>(src + 4);
                v[0] = (short)f2bf(r0.x * SCALE); v[1] = (short)f2bf(r0.y * SCALE);
                v[2] = (short)f2bf(r0.z * SCALE); v[3] = (short)f2bf(r0.w * SCALE);
                v[4] = (short)f2bf(r1.x * SCALE); v[5] = (short)f2bf(r1.y * SCALE);
                v[6] = (short)f2bf(r1.z * SCALE); v[7] = (short)f2bf(r1.w * SCALE);
            }
            bs[ks][nf] = v;
        }

    const short* agvs = (const short*)agv_x;
    short8v bv[2][4];
#pragma unroll
    for (int ks = 0; ks < 2; ++ks)
#pragma unroll
        for (int nf = 0; nf < 4; ++nf) {
            int d = nf * 16 + acol;
            short8v v = {};
#pragma unroll
            for (int i = 0; i < 8; ++i) {
                int a = ks * 32 + kgrp * 8 + i;
                if (a < AGENT)
                    v[i] = agvs[(((size_t)b * HEADS + h) * AGENT + a) * HD + d];
            }
            bv[ks][nf] = v;
        }

    __syncthreads();

    int tstart = half ? 25 : 0, tend = half ? 49 : 25;
    for (int t = tstart + wave; t < tend; t += 4) {
        int n0 = t * 16;
        const short* qrow = (const short*)qpre +
            ((size_t)(b * NPOS + n0 + acol)) * DIM + h * HD + kgrp * 8;
        short8v a0 = *reinterpret_cast<const short8v*>(qrow);
        short8v a1 = *reinterpret_cast<const short8v*>(qrow + 32);

        f32x4 accs[4] = {};
#pragma unroll
        for (int nf = 0; nf < 4; ++nf) {
            accs[nf] = __builtin_amdgcn_mfma_f32_16x16x32_bf16(a0, bs[0][nf], accs[nf], 0, 0, 0);
            accs[nf] = __builtin_amdgcn_mfma_f32_16x16x32_bf16(a1, bs[1][nf], accs[nf], 0, 0, 0);
        }

        float inv[4];
#pragma unroll
        for (int r = 0; r < 4; ++r) {
            int n = n0 + kgrp * 4 + r;
            float sarr[4];
            float m = -1e30f;
#pragma unroll
            for (int nf = 0; nf < 4; ++nf) {
                int a = nf * 16 + acol;
                float s = -1e30f;
                if (a < AGENT)
                    s = accs[nf][r] + bf2f(ab_x[((size_t)h * NPOS + n) * AGENT + a]);
                sarr[nf] = s;
                m = fmaxf(m, s);
            }
#pragma unroll
            for (int off = 1; off < 16; off <<= 1)
                m = fmaxf(m, __shfl_xor(m, off));
            float ls = 0.f;
#pragma unroll
            for (int nf = 0; nf < 4; ++nf) {
                float p = (sarr[nf] > -1e29f) ? __expf(sarr[nf] - m) : 0.f;
                sarr[nf] = p;
                ls += p;
            }
#pragma unroll
            for (int off = 1; off < 16; off <<= 1)
                ls += __shfl_xor(ls, off);
            inv[r] = 1.f / ls;
#pragma unroll
            for (int nf = 0; nf < 4; ++nf) {
                int a = nf * 16 + acol;
                if (a < AGENT)
                    pL[wave][kgrp * 4 + r][a] = (short)f2bf(sarr[nf]);
            }
        }

        short8v p0 = *reinterpret_cast<const short8v*>(&pL[wave][acol][kgrp * 8]);
        short8v p1 = *reinterpret_cast<const short8v*>(&pL[wave][acol][kgrp * 8 + 32]);

        f32x4 acco[4] = {};
#pragma unroll
        for (int nf = 0; nf < 4; ++nf) {
            acco[nf] = __builtin_amdgcn_mfma_f32_16x16x32_bf16(p0, bv[0][nf], acco[nf], 0, 0, 0);
            acco[nf] = __builtin_amdgcn_mfma_f32_16x16x32_bf16(p1, bv[1][nf], acco[nf], 0, 0, 0);
        }

#pragma unroll
        for (int r = 0; r < 4; ++r)
#pragma unroll
            for (int nf = 0; nf < 4; ++nf)
                oL[wave][kgrp * 4 + r][nf * 16 + acol] = acco[nf][r] * inv[r];

#pragma unroll
        for (int it2 = 0; it2 < 2; ++it2) {
            int item = lane + 64 * it2;       // 0..127
            int rl = item >> 3, d8 = item & 7;
            int n = n0 + rl;
            int i = n / WW, j = n % WW;
            float accv[8];
            {
                float4 o0 = *reinterpret_cast<const float4*>(&oL[wave][rl][d8 * 8]);
                float4 o1 = *reinterpret_cast<const float4*>(&oL[wave][rl][d8 * 8 + 4]);
                accv[0] = o0.x + cbS[d8 * 8 + 0]; accv[1] = o0.y + cbS[d8 * 8 + 1];
                accv[2] = o0.z + cbS[d8 * 8 + 2]; accv[3] = o0.w + cbS[d8 * 8 + 3];
                accv[4] = o1.x + cbS[d8 * 8 + 4]; accv[5] = o1.y + cbS[d8 * 8 + 5];
                accv[6] = o1.z + cbS[d8 * 8 + 6]; accv[7] = o1.w + cbS[d8 * 8 + 7];
            }
#pragma unroll
            for (int di = -1; di <= 1; ++di) {
                int ii = i + di;
                if (ii < 0 || ii >= HH) continue;
#pragma unroll
                for (int dj = -1; dj <= 1; ++dj) {
                    int jj = j + dj;
                    if (jj < 0 || jj >= WW) continue;
                    short8v vv = *reinterpret_cast<const short8v*>(
                        (const short*)kv_own + ((size_t)(b * NPOS + ii * WW + jj)) * (2 * DIM) + DIM + h * HD + d8 * 8);
                    int tap = (di + 1) * 3 + (dj + 1);
#pragma unroll
                    for (int u = 0; u < 8; ++u)
                        accv[u] += wS[tap][d8 * 8 + u] * bfs2f(vv[u]);
                }
            }
            short8v ov;
#pragma unroll
            for (int u = 0; u < 8; ++u) ov[u] = (short)f2bf(accv[u]);
            *reinterpret_cast<short8v*>((short*)qpre +
                ((size_t)(b * NPOS + n)) * DIM + h * HD + d8 * 8) = ov;
        }
    }
}

// ---------------------------------------------------------------------------
extern "C" void kernel_launch(void* const* d_in, const int* in_sizes, int n_in,
                              void* d_out, int out_size, void* d_ws, size_t ws_size,
                              hipStream_t stream)
{
    const float* rgb_fea    = (const float*)d_in[0];
    const float* depth_fea  = (const float*)d_in[1];
    const float* rgb_q_w    = (const float*)d_in[2];
    const float* rgb_kv_w   = (const float*)d_in[3];
    const float* rgb_proj_w = (const float*)d_in[4];
    const float* rgb_proj_b = (const float*)d_in[5];
    const float* depth_q_w    = (const float*)d_in[6];
    const float* depth_kv_w   = (const float*)d_in[7];
    const float* depth_proj_w = (const float*)d_in[8];
    const float* depth_proj_b = (const float*)d_in[9];
    const float* rgb_dwc_w   = (const float*)d_in[10];
    const float* rgb_dwc_b   = (const float*)d_in[11];
    const float* depth_dwc_w = (const float*)d_in[12];
    const float* depth_dwc_b = (const float*)d_in[13];
    const float* rgb_an   = (const float*)d_in[14];
    const float* rgb_na   = (const float*)d_in[15];
    const float* rgb_ah_b = (const float*)d_in[16];
    const float* rgb_aw_b = (const float*)d_in[17];
    const float* rgb_ha_b = (const float*)d_in[18];
    const float* rgb_wa_b = (const float*)d_in[19];
    const float* depth_an   = (const float*)d_in[20];
    const float* depth_na   = (const float*)d_in[21];
    const float* depth_ah_b = (const float*)d_in[22];
    const float* depth_aw_b = (const float*)d_in[23];
    const float* depth_ha_b = (const float*)d_in[24];
    const float* depth_wa_b = (const float*)d_in[25];

    char* ws = (char*)d_ws;
    size_t off = 0;
    auto alloc = [&](size_t bytes) -> void* {
        void* p = ws + off;
        off += (bytes + 255) & ~(size_t)255;
        return p;
    };
    bf16* rgb_q    = (bf16*)alloc((size_t)MROWS * DIM * 2);
    bf16* depth_q  = (bf16*)alloc((size_t)MROWS * DIM * 2);
    bf16* rgb_kv   = (bf16*)alloc((size_t)MROWS * 2 * DIM * 2);
    bf16* depth_kv = (bf16*)alloc((size_t)MROWS * 2 * DIM * 2);
    bf16* rgb_pb    = (bf16*)alloc((size_t)HEADS * AGENT * NPOS * 2);
    bf16* depth_pb  = (bf16*)alloc((size_t)HEADS * AGENT * NPOS * 2);
    bf16* rgb_ab    = (bf16*)alloc((size_t)HEADS * NPOS * AGENT * 2);
    bf16* depth_ab  = (bf16*)alloc((size_t)HEADS * NPOS * AGENT * 2);
    bf16* rgb_agv   = (bf16*)alloc((size_t)BATCH * HEADS * AGENT * HD * 2);
    bf16* depth_agv = (bf16*)alloc((size_t)BATCH * HEADS * AGENT * HD * 2);
    bf16* proj_wt_r = (bf16*)alloc((size_t)DIM * DIM * 2);
    bf16* proj_wt_d = (bf16*)alloc((size_t)DIM * DIM * 2);
    size_t ubase = off;
    bf16* q_wt_r  = (bf16*)alloc((size_t)DIM * DIM * 2);
    bf16* kv_wt_r = (bf16*)alloc((size_t)DIM * 2 * DIM * 2);
    bf16* q_wt_d  = (bf16*)alloc((size_t)DIM * DIM * 2);
    bf16* kv_wt_d = (bf16*)alloc((size_t)DIM * 2 * DIM * 2);
    off = ubase;  // alias
    float* rgb_ahp   = (float*)alloc((size_t)BATCH * AGENT * DIM * 4);
    float* depth_ahp = (float*)alloc((size_t)BATCH * AGENT * DIM * 4);

    // d_out doubles as scratch for the bf16-converted activations
    bf16* fea_bf_r = (bf16*)d_out;
    bf16* fea_bf_d = fea_bf_r + (size_t)MROWS * DIM;

    dim3 blk(256);
    int n8 = MROWS * DIM / 8;

    // 0) activation f32->bf16 + weight transposes
    convert_bf16<<<(n8 + 255) / 256, blk, 0, stream>>>(rgb_fea, fea_bf_r, n8);
    convert_bf16<<<(n8 + 255) / 256, blk, 0, stream>>>(depth_fea, fea_bf_d, n8);
    transpose_w_bf16<<<dim3(24, 24), blk, 0, stream>>>(rgb_q_w, q_wt_r, DIM, DIM);
    transpose_w_bf16<<<dim3(48, 24), blk, 0, stream>>>(rgb_kv_w, kv_wt_r, DIM, 2 * DIM);
    transpose_w_bf16<<<dim3(24, 24), blk, 0, stream>>>(depth_q_w, q_wt_d, DIM, DIM);
    transpose_w_bf16<<<dim3(48, 24), blk, 0, stream>>>(depth_kv_w, kv_wt_d, DIM, 2 * DIM);
    transpose_w_bf16<<<dim3(24, 24), blk, 0, stream>>>(rgb_proj_w, proj_wt_r, DIM, DIM);
    transpose_w_bf16<<<dim3(24, 24), blk, 0, stream>>>(depth_proj_w, proj_wt_d, DIM, DIM);

    // 1) q / kv projections (pure bf16 MFMA, 2-phase pipelined staging)
    gemm_mfma<false><<<dim3(6, 196), blk, 0, stream>>>(fea_bf_r, q_wt_r, nullptr, rgb_q, MROWS, DIM, DIM);
    gemm_mfma<false><<<dim3(6, 196), blk, 0, stream>>>(fea_bf_d, q_wt_d, nullptr, depth_q, MROWS, DIM, DIM);
    gemm_mfma<false><<<dim3(12, 196), blk, 0, stream>>>(fea_bf_r, kv_wt_r, nullptr, rgb_kv, MROWS, 2 * DIM, DIM);
    gemm_mfma<false><<<dim3(12, 196), blk, 0, stream>>>(fea_bf_d, kv_wt_d, nullptr, depth_kv, MROWS, 2 * DIM, DIM);

    // 2) agent pooling of q
    pool_kernel<<<(BATCH * AGENT * DIM + 255) / 256, blk, 0, stream>>>(rgb_q, rgb_ahp);
    pool_kernel<<<(BATCH * AGENT * DIM + 255) / 256, blk, 0, stream>>>(depth_q, depth_ahp);

    // 3) position biases
    pos_bias_kernel<<<(HEADS * AGENT * NPOS + 255) / 256, blk, 0, stream>>>(rgb_an, rgb_ah_b, rgb_aw_b, rgb_pb);
    pos_bias_kernel<<<(HEADS * AGENT * NPOS + 255) / 256, blk, 0, stream>>>(depth_an, depth_ah_b, depth_aw_b, depth_pb);
    ag_bias_kernel<<<(HEADS * NPOS * AGENT + 255) / 256, blk, 0, stream>>>(rgb_na, rgb_ha_b, rgb_wa_b, rgb_ab);
    ag_bias_kernel<<<(HEADS * NPOS * AGENT + 255) / 256, blk, 0, stream>>>(depth_na, depth_ha_b, depth_wa_b, depth_ab);

    // 4) cross-modal agent aggregation (MFMA flash)
    agent_attn3<<<BATCH * HEADS, blk, 0, stream>>>(depth_ahp, rgb_kv, rgb_pb, depth_agv);
    agent_attn3<<<BATCH * HEADS, blk, 0, stream>>>(rgb_ahp, depth_kv, depth_pb, rgb_agv);

    // 5) agent broadcast (MFMA) + fused vectorized depthwise conv
    q_attn_mfma<<<BATCH * HEADS * 2, blk, 0, stream>>>(rgb_q, rgb_kv, depth_ahp, depth_ab, depth_agv,
                                                       rgb_dwc_w, rgb_dwc_b);
    q_attn_mfma<<<BATCH * HEADS * 2, blk, 0, stream>>>(depth_q, depth_kv, rgb_ahp, rgb_ab, rgb_agv,
                                                       depth_dwc_w, depth_dwc_b);

    // 6) output projections (overwrite d_out scratch with final results)
    float* out = (float*)d_out;
    gemm_mfma<true><<<dim3(6, 196), blk, 0, stream>>>(rgb_q, proj_wt_r, rgb_proj_b, out, MROWS, DIM, DIM);
    gemm_mfma<true><<<dim3(6, 196), blk, 0, stream>>>(depth_q, proj_wt_d, depth_proj_b,
                                                      out + (size_t)MROWS * DIM, MROWS, DIM, DIM);
}

// Round 13
// 696.963 us; speedup vs baseline: 1.0828x; 1.0828x over previous
//
#include <hip/hip_runtime.h>
#include <hip/hip_bf16.h>

#define BATCH 32
#define NPOS 784
#define DIM 768
#define HEADS 12
#define HD 64
#define AGENT 49
#define HH 28
#define WW 28
#define MROWS (BATCH*NPOS)   // 25088
#define SCALE 0.125f

using bf16 = __hip_bfloat16;
typedef __attribute__((ext_vector_type(4))) float f32x4;
typedef __attribute__((ext_vector_type(8))) short short8v;

__device__ __forceinline__ float bf2f(bf16 x) { return __bfloat162float(x); }
__device__ __forceinline__ float bfs2f(short s) {
    unsigned int u = ((unsigned int)(unsigned short)s) << 16;
    return __uint_as_float(u);
}
__device__ __forceinline__ unsigned short f2bf(float x) {
    unsigned int u = __float_as_uint(x);
    unsigned int r = (u + 0x7fffu + ((u >> 16) & 1u)) >> 16;
    return (unsigned short)r;
}

// async global->LDS, 16B per lane (dest must be wave-uniform base + lane*16)
#define GLOAD_LDS16(g, l) __builtin_amdgcn_global_load_lds( \
    (const __attribute__((address_space(1))) unsigned int*)(g), \
    (__attribute__((address_space(3))) unsigned int*)(l), 16, 0, 0)

// ---------------------------------------------------------------------------
// f32 -> bf16 convert, two tensors in one dispatch
// ---------------------------------------------------------------------------
__global__ __launch_bounds__(256) void convert_bf16_2(
    const float* __restrict__ src0, bf16* __restrict__ dst0,
    const float* __restrict__ src1, bf16* __restrict__ dst1, int n8)
{
    int idx = blockIdx.x * 256 + threadIdx.x;
    if (idx >= 2 * n8) return;
    int sel = idx >= n8;
    int li = idx - sel * n8;
    const float* p = (sel ? src1 : src0) + (size_t)li * 8;
    float4 r0 = *reinterpret_cast<const float4*>(p);
    float4 r1 = *reinterpret_cast<const float4*>(p + 4);
    short8v v;
    v[0] = (short)f2bf(r0.x); v[1] = (short)f2bf(r0.y);
    v[2] = (short)f2bf(r0.z); v[3] = (short)f2bf(r0.w);
    v[4] = (short)f2bf(r1.x); v[5] = (short)f2bf(r1.y);
    v[6] = (short)f2bf(r1.z); v[7] = (short)f2bf(r1.w);
    *reinterpret_cast<short8v*>((short*)(sel ? dst1 : dst0) + (size_t)li * 8) = v;
}

// ---------------------------------------------------------------------------
// Transpose+convert pair: W [K][N] f32 -> Wt [N][K] bf16 (two weights/launch)
// ---------------------------------------------------------------------------
__global__ __launch_bounds__(256) void transpose_w_bf16_2(
    const float* __restrict__ W0, bf16* __restrict__ Wt0,
    const float* __restrict__ W1, bf16* __restrict__ Wt1, int K, int N)
{
    __shared__ float t[32][33];
    int gyh = gridDim.y >> 1;
    int sel = blockIdx.y >= gyh;
    const float* W = sel ? W1 : W0;
    bf16* Wt = sel ? Wt1 : Wt0;
    int tx = threadIdx.x & 31, ty = threadIdx.x >> 5;
    int k0 = (blockIdx.y - sel * gyh) * 32, n0 = blockIdx.x * 32;
#pragma unroll
    for (int i = 0; i < 4; ++i)
        t[ty + 8 * i][tx] = W[(size_t)(k0 + ty + 8 * i) * N + n0 + tx];
    __syncthreads();
#pragma unroll
    for (int i = 0; i < 4; ++i)
        Wt[(size_t)(n0 + ty + 8 * i) * K + k0 + tx] = __float2bfloat16(t[tx][ty + 8 * i]);
}

// ---------------------------------------------------------------------------
// MFMA GEMM (R11 single-buffer structure, merged rgb+depth problems):
// C = A @ Bt^T per problem; blockIdx.y in [0,gyh) -> problem 0, else 1.
// 128x128 tile, BK=64, global_load_lds w16, XOR-swizzled LDS, bijective XCD
// grid swizzle over the MERGED grid (nwg%8==0). Direct scalar C-stores.
// ---------------------------------------------------------------------------
template<bool OUTF32>
__global__ __launch_bounds__(256) void gemm_mfma(
    const bf16* __restrict__ A0, const bf16* __restrict__ Bt0,
    const float* __restrict__ bias0, void* __restrict__ Cp0,
    const bf16* __restrict__ A1, const bf16* __restrict__ Bt1,
    const float* __restrict__ bias1, void* __restrict__ Cp1,
    int M, int N, int K)
{
    __shared__ __align__(16) short As[128 * 64];
    __shared__ __align__(16) short Bs[128 * 64];

    int tid = threadIdx.x;
    int wave = tid >> 6, lane = tid & 63;

    // bijective XCD swizzle over merged grid
    int gx = gridDim.x;
    int gyh = gridDim.y >> 1;
    int nwg = gx * gridDim.y;
    int bid = blockIdx.y * gx + blockIdx.x;
    int cpx = nwg >> 3;
    int nb = (bid & 7) * cpx + (bid >> 3);
    int rowblk = nb / gx;
    int prob = rowblk >= gyh;
    int m0 = (rowblk - prob * gyh) * 128, n0 = (nb % gx) * 128;

    const short* Ab  = (const short*)(prob ? A1 : A0);
    const short* Btb = (const short*)(prob ? Bt1 : Bt0);
    const float* bias = prob ? bias1 : bias0;
    void* Cp = prob ? Cp1 : Cp0;

    int wm = (wave >> 1) * 64, wn = (wave & 1) * 64;
    int acol = lane & 15, kgrp = lane >> 4;

    f32x4 acc[4][4] = {};

    for (int k0 = 0; k0 < K; k0 += 64) {
#pragma unroll
        for (int it = 0; it < 4; ++it) {
            int idx = tid + 256 * it;          // 1024 chunks of 16B
            int row = idx >> 3, seg = idx & 7;
            int sseg = seg ^ (row & 7);        // pre-swizzled source
            GLOAD_LDS16(Ab + (size_t)(m0 + row) * K + k0 + sseg * 8, &As[idx * 8]);
        }
#pragma unroll
        for (int it = 0; it < 4; ++it) {
            int idx = tid + 256 * it;
            int row = idx >> 3, seg = idx & 7;
            int sseg = seg ^ (row & 7);
            GLOAD_LDS16(Btb + (size_t)(n0 + row) * K + k0 + sseg * 8, &Bs[idx * 8]);
        }
        __syncthreads();

#pragma unroll
        for (int kk = 0; kk < 2; ++kk) {
            short8v af[4], bfr[4];
#pragma unroll
            for (int mf = 0; mf < 4; ++mf) {
                int row = wm + mf * 16 + acol;
                int seg = (kk * 4 + kgrp) ^ (row & 7);
                af[mf] = *reinterpret_cast<const short8v*>(&As[row * 64 + seg * 8]);
            }
#pragma unroll
            for (int nf = 0; nf < 4; ++nf) {
                int row = wn + nf * 16 + acol;
                int seg = (kk * 4 + kgrp) ^ (row & 7);
                bfr[nf] = *reinterpret_cast<const short8v*>(&Bs[row * 64 + seg * 8]);
            }
#pragma unroll
            for (int mf = 0; mf < 4; ++mf)
#pragma unroll
                for (int nf = 0; nf < 4; ++nf)
                    acc[mf][nf] = __builtin_amdgcn_mfma_f32_16x16x32_bf16(
                        af[mf], bfr[nf], acc[mf][nf], 0, 0, 0);
        }
        __syncthreads();
    }

    int rgrp = kgrp * 4, cidx = acol;
#pragma unroll
    for (int mf = 0; mf < 4; ++mf)
#pragma unroll
        for (int nf = 0; nf < 4; ++nf)
#pragma unroll
            for (int r = 0; r < 4; ++r) {
                int row = m0 + wm + mf * 16 + rgrp + r;
                int col = n0 + wn + nf * 16 + cidx;
                float v = acc[mf][nf][r];
                if constexpr (OUTF32)
                    ((float*)Cp)[(size_t)row * N + col] = v + bias[col];
                else
                    ((bf16*)Cp)[(size_t)row * N + col] = __float2bfloat16(v);
            }
}

// ---------------------------------------------------------------------------
// Pool pair: ahp[b][a][c] = mean over 4x4 block of q[b][n][c]
// ---------------------------------------------------------------------------
__global__ void pool_kernel_2(const bf16* __restrict__ q0, float* __restrict__ ahp0,
                              const bf16* __restrict__ q1, float* __restrict__ ahp1)
{
    int idx = blockIdx.x * 256 + threadIdx.x;
    int tot = BATCH * AGENT * DIM;
    if (idx >= 2 * tot) return;
    int sel = idx >= tot;
    int li = idx - sel * tot;
    const bf16* q = sel ? q1 : q0;
    float* ahp = sel ? ahp1 : ahp0;
    int c = li % DIM;
    int a = (li / DIM) % AGENT;
    int b = li / (DIM * AGENT);
    int ai = a / 7, aj = a % 7;
    float s = 0.f;
#pragma unroll
    for (int u = 0; u < 4; ++u)
#pragma unroll
        for (int v = 0; v < 4; ++v) {
            int n = (ai * 4 + u) * WW + (aj * 4 + v);
            s += bf2f(q[((size_t)b * NPOS + n) * DIM + c]);
        }
    ahp[li] = s * (1.f / 16.f);
}

// ---------------------------------------------------------------------------
// Bilinear 7->28 upsample, half-pixel centers, edge clamp
// ---------------------------------------------------------------------------
__device__ __forceinline__ float bilerp7(const float* __restrict__ img, int i, int j)
{
    float si = 0.25f * i - 0.375f, sj = 0.25f * j - 0.375f;
    int i0 = (int)floorf(si); float fi = si - i0;
    int j0 = (int)floorf(sj); float fj = sj - j0;
    int i0c = min(max(i0, 0), 6), i1c = min(max(i0 + 1, 0), 6);
    int j0c = min(max(j0, 0), 6), j1c = min(max(j0 + 1, 0), 6);
    float v00 = img[i0c * 7 + j0c], v01 = img[i0c * 7 + j1c];
    float v10 = img[i1c * 7 + j0c], v11 = img[i1c * 7 + j1c];
    return (1.f - fi) * ((1.f - fj) * v00 + fj * v01) + fi * ((1.f - fj) * v10 + fj * v11);
}

__global__ void pos_bias_kernel_2(
    const float* __restrict__ an0, const float* __restrict__ ah_b0,
    const float* __restrict__ aw_b0, bf16* __restrict__ pb0,
    const float* __restrict__ an1, const float* __restrict__ ah_b1,
    const float* __restrict__ aw_b1, bf16* __restrict__ pb1)
{
    int idx = blockIdx.x * 256 + threadIdx.x;
    int tot = HEADS * AGENT * NPOS;
    if (idx >= 2 * tot) return;
    int sel = idx >= tot;
    int li = idx - sel * tot;
    const float* an = sel ? an1 : an0;
    const float* ah_b = sel ? ah_b1 : ah_b0;
    const float* aw_b = sel ? aw_b1 : aw_b0;
    bf16* pb = sel ? pb1 : pb0;
    int n = li % NPOS;
    int a = (li / NPOS) % AGENT;
    int h = li / (NPOS * AGENT);
    int i = n / WW, j = n % WW;
    float v = bilerp7(an + (size_t)(h * AGENT + a) * 49, i, j);
    v += ah_b[(h * AGENT + a) * HH + i] + aw_b[(h * AGENT + a) * WW + j];
    pb[li] = __float2bfloat16(v);
}

__global__ void ag_bias_kernel_2(
    const float* __restrict__ na0, const float* __restrict__ ha_b0,
    const float* __restrict__ wa_b0, bf16* __restrict__ ab0,
    const float* __restrict__ na1, const float* __restrict__ ha_b1,
    const float* __restrict__ wa_b1, bf16* __restrict__ ab1)
{
    int idx = blockIdx.x * 256 + threadIdx.x;
    int tot = HEADS * NPOS * AGENT;
    if (idx >= 2 * tot) return;
    int sel = idx >= tot;
    int li = idx - sel * tot;
    const float* na = sel ? na1 : na0;
    const float* ha_b = sel ? ha_b1 : ha_b0;
    const float* wa_b = sel ? wa_b1 : wa_b0;
    bf16* ab = sel ? ab1 : ab0;
    int a = li % AGENT;
    int n = (li / AGENT) % NPOS;
    int h = li / (AGENT * NPOS);
    int i = n / WW, j = n % WW;
    float v = bilerp7(na + (size_t)(h * AGENT + a) * 49, i, j);
    v += ha_b[(h * HH + i) * AGENT + a] + wa_b[(h * WW + j) * AGENT + a];
    ab[li] = __float2bfloat16(v);
}

// ---------------------------------------------------------------------------
// Agent attention v3 (full MFMA), both modalities in one dispatch.
// blockIdx.x < BATCH*HEADS -> problem 0, else problem 1.
// ---------------------------------------------------------------------------
__global__ __launch_bounds__(256, 2) void agent_attn3(
    const float* __restrict__ ahp0, const bf16* __restrict__ kv0,
    const bf16* __restrict__ pb0, bf16* __restrict__ agent_v0,
    const float* __restrict__ ahp1, const bf16* __restrict__ kv1,
    const bf16* __restrict__ pb1, bf16* __restrict__ agent_v1)
{
    __shared__ __align__(16) char smem[75776];
    short (*pL)[64][72]  = (short (*)[64][72])smem;            // [4][64][72]
    short (*VtL)[64][72] = (short (*)[64][72])(smem + 36864);  // [4][64][72]
    float (*Om)[64][66]  = (float (*)[64][66])smem;            // aliases pL/VtL
    float (*mw)[64]      = (float (*)[64])(smem + 73728);
    float (*lw)[64]      = (float (*)[64])(smem + 74752);

    int sel = blockIdx.x >= BATCH * HEADS;
    int blk = blockIdx.x - sel * BATCH * HEADS;
    const float* ahp = sel ? ahp1 : ahp0;
    const bf16* kv = sel ? kv1 : kv0;
    const bf16* pb = sel ? pb1 : pb0;
    bf16* agent_v = sel ? agent_v1 : agent_v0;

    int tid = threadIdx.x;
    int wave = tid >> 6, lane = tid & 63;
    int acol = lane & 15, kgrp = lane >> 4;
    int h = blk % HEADS;
    int b = blk / HEADS;
    const short* kvs = (const short*)kv;
    const bf16* pbh = pb + (size_t)h * AGENT * NPOS;

    short8v qa[2][4];
#pragma unroll
    for (int ks = 0; ks < 2; ++ks)
#pragma unroll
        for (int mf = 0; mf < 4; ++mf) {
            int a = mf * 16 + acol;
            short8v v = {};
            if (a < AGENT) {
                const float* src = ahp + ((size_t)b * AGENT + a) * DIM + h * HD + ks * 32 + kgrp * 8;
                float4 r0 = *reinterpret_cast<const float4*>(src);
                float4 r1 = *reinterpret_cast<const float4*>(src + 4);
                v[0] = (short)f2bf(r0.x * SCALE); v[1] = (short)f2bf(r0.y * SCALE);
                v[2] = (short)f2bf(r0.z * SCALE); v[3] = (short)f2bf(r0.w * SCALE);
                v[4] = (short)f2bf(r1.x * SCALE); v[5] = (short)f2bf(r1.y * SCALE);
                v[6] = (short)f2bf(r1.z * SCALE); v[7] = (short)f2bf(r1.w * SCALE);
            }
            qa[ks][mf] = v;
        }

    float mrun[16], lrun[16];
#pragma unroll
    for (int i = 0; i < 16; ++i) { mrun[i] = -1e30f; lrun[i] = 0.f; }
    f32x4 accO[4][4] = {};

    for (int t = wave; t < 13; t += 4) {
        int n0 = t * 64;
        {
            int p = lane & 31, dh = lane >> 5;
            const short* v0p = kvs + (size_t)(b * NPOS + n0 + 2 * p) * (2 * DIM) + DIM + h * HD + dh * 32;
#pragma unroll
            for (int s = 0; s < 4; ++s) {
                short8v va = {}, vb = {};
                if (n0 + 2 * p < NPOS)     va = *reinterpret_cast<const short8v*>(v0p + s * 8);
                if (n0 + 2 * p + 1 < NPOS) vb = *reinterpret_cast<const short8v*>(v0p + 2 * DIM + s * 8);
#pragma unroll
                for (int u = 0; u < 8; ++u) {
                    int d = dh * 32 + s * 8 + u;
                    unsigned int w = ((unsigned int)(unsigned short)va[u]) |
                                     (((unsigned int)(unsigned short)vb[u]) << 16);
                    *reinterpret_cast<unsigned int*>(&VtL[wave][d][2 * p]) = w;
                }
            }
        }

        short8v kb[2][4];
#pragma unroll
        for (int nf = 0; nf < 4; ++nf) {
            int n = n0 + nf * 16 + acol;
            bool val = (n < NPOS);
            const short* kp = kvs + (size_t)(b * NPOS + n) * (2 * DIM) + h * HD + kgrp * 8;
#pragma unroll
            for (int ks = 0; ks < 2; ++ks) {
                short8v v = {};
                if (val) v = *reinterpret_cast<const short8v*>(kp + ks * 32);
                kb[ks][nf] = v;
            }
        }

        f32x4 accS[4][4] = {};
#pragma unroll
        for (int mf = 0; mf < 4; ++mf)
#pragma unroll
            for (int nf = 0; nf < 4; ++nf) {
                accS[mf][nf] = __builtin_amdgcn_mfma_f32_16x16x32_bf16(qa[0][mf], kb[0][nf], accS[mf][nf], 0, 0, 0);
                accS[mf][nf] = __builtin_amdgcn_mfma_f32_16x16x32_bf16(qa[1][mf], kb[1][nf], accS[mf][nf], 0, 0, 0);
            }

#pragma unroll
        for (int mf = 0; mf < 4; ++mf)
#pragma unroll
            for (int r = 0; r < 4; ++r) {
                int a = mf * 16 + kgrp * 4 + r;
                float s[4];
                float mt = -1e30f;
#pragma unroll
                for (int nf = 0; nf < 4; ++nf) {
                    int n = n0 + nf * 16 + acol;
                    float sv = -1e30f;
                    if (n < NPOS) {
                        sv = accS[mf][nf][r];
                        if (a < AGENT) sv += bf2f(pbh[(size_t)a * NPOS + n]);
                    }
                    s[nf] = sv;
                    mt = fmaxf(mt, sv);
                }
#pragma unroll
                for (int off = 1; off < 16; off <<= 1)
                    mt = fmaxf(mt, __shfl_xor(mt, off));
                float mnew = fmaxf(mrun[mf * 4 + r], mt);
                float fac = __expf(mrun[mf * 4 + r] - mnew);
                float ps = 0.f;
#pragma unroll
                for (int nf = 0; nf < 4; ++nf) {
                    float pv = (s[nf] > -1e29f) ? __expf(s[nf] - mnew) : 0.f;
                    ps += pv;
                    pL[wave][a][nf * 16 + acol] = (short)f2bf(pv);
                }
#pragma unroll
                for (int off = 1; off < 16; off <<= 1)
                    ps += __shfl_xor(ps, off);
                mrun[mf * 4 + r] = mnew;
                lrun[mf * 4 + r] = lrun[mf * 4 + r] * fac + ps;
#pragma unroll
                for (int df = 0; df < 4; ++df) accO[mf][df][r] *= fac;
            }

        short8v vb2[2][4];
#pragma unroll
        for (int ks = 0; ks < 2; ++ks)
#pragma unroll
            for (int df = 0; df < 4; ++df)
                vb2[ks][df] = *reinterpret_cast<const short8v*>(
                    &VtL[wave][df * 16 + acol][ks * 32 + kgrp * 8]);
#pragma unroll
        for (int mf = 0; mf < 4; ++mf) {
#pragma unroll
            for (int ks = 0; ks < 2; ++ks) {
                short8v pa = *reinterpret_cast<const short8v*>(
                    &pL[wave][mf * 16 + acol][ks * 32 + kgrp * 8]);
#pragma unroll
                for (int df = 0; df < 4; ++df)
                    accO[mf][df] = __builtin_amdgcn_mfma_f32_16x16x32_bf16(pa, vb2[ks][df], accO[mf][df], 0, 0, 0);
            }
        }
    }

    if (acol == 0) {
#pragma unroll
        for (int mf = 0; mf < 4; ++mf)
#pragma unroll
            for (int r = 0; r < 4; ++r) {
                mw[wave][mf * 16 + kgrp * 4 + r] = mrun[mf * 4 + r];
                lw[wave][mf * 16 + kgrp * 4 + r] = lrun[mf * 4 + r];
            }
    }
    __syncthreads();
#pragma unroll
    for (int mf = 0; mf < 4; ++mf)
#pragma unroll
        for (int df = 0; df < 4; ++df)
#pragma unroll
            for (int r = 0; r < 4; ++r)
                Om[wave][mf * 16 + kgrp * 4 + r][df * 16 + acol] = accO[mf][df][r];
    __syncthreads();

    for (int idx = tid; idx < AGENT * HD; idx += 256) {
        int a = idx >> 6, d = idx & 63;
        float m = fmaxf(fmaxf(mw[0][a], mw[1][a]), fmaxf(mw[2][a], mw[3][a]));
        float l = 0.f, o = 0.f;
#pragma unroll
        for (int w = 0; w < 4; ++w) {
            float f = __expf(mw[w][a] - m);
            l += f * lw[w][a];
            o += f * Om[w][a][d];
        }
        ((short*)agent_v)[(((size_t)b * HEADS + h) * AGENT + a) * HD + d] = (short)f2bf(o / l);
    }
}

// ---------------------------------------------------------------------------
// Q attention via MFMA + fused depthwise conv, both modalities in one dispatch.
// blockIdx.x < BATCH*HEADS*2 -> problem 0, else problem 1.
// ---------------------------------------------------------------------------
__global__ __launch_bounds__(256) void q_attn_mfma(
    bf16* qpre0, const bf16* __restrict__ kv_own0,
    const float* __restrict__ ahp_x0, const bf16* __restrict__ ab_x0,
    const bf16* __restrict__ agv_x0,
    const float* __restrict__ dwc_w0, const float* __restrict__ dwc_b0,
    bf16* qpre1, const bf16* __restrict__ kv_own1,
    const float* __restrict__ ahp_x1, const bf16* __restrict__ ab_x1,
    const bf16* __restrict__ agv_x1,
    const float* __restrict__ dwc_w1, const float* __restrict__ dwc_b1)
{
    __shared__ short pL[4][16][72];
    __shared__ float oL[4][16][68];
    __shared__ float wS[9][64];
    __shared__ float cbS[64];

    int sel = blockIdx.x >= BATCH * HEADS * 2;
    int blk = blockIdx.x - sel * BATCH * HEADS * 2;
    bf16* qpre = sel ? qpre1 : qpre0;
    const bf16* kv_own = sel ? kv_own1 : kv_own0;
    const float* ahp_x = sel ? ahp_x1 : ahp_x0;
    const bf16* ab_x = sel ? ab_x1 : ab_x0;
    const bf16* agv_x = sel ? agv_x1 : agv_x0;
    const float* dwc_w = sel ? dwc_w1 : dwc_w0;
    const float* dwc_b = sel ? dwc_b1 : dwc_b0;

    int half = blk & 1;
    int h = (blk >> 1) % HEADS;
    int b = blk / (2 * HEADS);
    int tid = threadIdx.x;
    int wave = tid >> 6, lane = tid & 63;
    int acol = lane & 15, kgrp = lane >> 4;

    for (int i = tid; i < 9 * 64; i += 256)
        wS[i >> 6][i & 63] = dwc_w[(i >> 6) * DIM + h * HD + (i & 63)];
    if (tid < 64) cbS[tid] = dwc_b[h * HD + tid];
    for (int i = tid; i < 4 * 16 * 72; i += 256)
        ((short*)pL)[i] = 0;

    short8v bs[2][4];
#pragma unroll
    for (int ks = 0; ks < 2; ++ks)
#pragma unroll
        for (int nf = 0; nf < 4; ++nf) {
            int a = nf * 16 + acol;
            short8v v = {};
            if (a < AGENT) {
                const float* src = ahp_x + ((size_t)b * AGENT + a) * DIM + h * HD + ks * 32 + kgrp * 8;
                float4 r0 = *reinterpret_cast<const float4*>(src);
                float4 r1 = *reinterpret_cast<const float4*>(src + 4);
                v[0] = (short)f2bf(r0.x * SCALE); v[1] = (short)f2bf(r0.y * SCALE);
                v[2] = (short)f2bf(r0.z * SCALE); v[3] = (short)f2bf(r0.w * SCALE);
                v[4] = (short)f2bf(r1.x * SCALE); v[5] = (short)f2bf(r1.y * SCALE);
                v[6] = (short)f2bf(r1.z * SCALE); v[7] = (short)f2bf(r1.w * SCALE);
            }
            bs[ks][nf] = v;
        }

    const short* agvs = (const short*)agv_x;
    short8v bv[2][4];
#pragma unroll
    for (int ks = 0; ks < 2; ++ks)
#pragma unroll
        for (int nf = 0; nf < 4; ++nf) {
            int d = nf * 16 + acol;
            short8v v = {};
#pragma unroll
            for (int i = 0; i < 8; ++i) {
                int a = ks * 32 + kgrp * 8 + i;
                if (a < AGENT)
                    v[i] = agvs[(((size_t)b * HEADS + h) * AGENT + a) * HD + d];
            }
            bv[ks][nf] = v;
        }

    __syncthreads();

    int tstart = half ? 25 : 0, tend = half ? 49 : 25;
    for (int t = tstart + wave; t < tend; t += 4) {
        int n0 = t * 16;
        const short* qrow = (const short*)qpre +
            ((size_t)(b * NPOS + n0 + acol)) * DIM + h * HD + kgrp * 8;
        short8v a0 = *reinterpret_cast<const short8v*>(qrow);
        short8v a1 = *reinterpret_cast<const short8v*>(qrow + 32);

        f32x4 accs[4] = {};
#pragma unroll
        for (int nf = 0; nf < 4; ++nf) {
            accs[nf] = __builtin_amdgcn_mfma_f32_16x16x32_bf16(a0, bs[0][nf], accs[nf], 0, 0, 0);
            accs[nf] = __builtin_amdgcn_mfma_f32_16x16x32_bf16(a1, bs[1][nf], accs[nf], 0, 0, 0);
        }

        float inv[4];
#pragma unroll
        for (int r = 0; r < 4; ++r) {
            int n = n0 + kgrp * 4 + r;
            float sarr[4];
            float m = -1e30f;
#pragma unroll
            for (int nf = 0; nf < 4; ++nf) {
                int a = nf * 16 + acol;
                float s = -1e30f;
                if (a < AGENT)
                    s = accs[nf][r] + bf2f(ab_x[((size_t)h * NPOS + n) * AGENT + a]);
                sarr[nf] = s;
                m = fmaxf(m, s);
            }
#pragma unroll
            for (int off = 1; off < 16; off <<= 1)
                m = fmaxf(m, __shfl_xor(m, off));
            float ls = 0.f;
#pragma unroll
            for (int nf = 0; nf < 4; ++nf) {
                float p = (sarr[nf] > -1e29f) ? __expf(sarr[nf] - m) : 0.f;
                sarr[nf] = p;
                ls += p;
            }
#pragma unroll
            for (int off = 1; off < 16; off <<= 1)
                ls += __shfl_xor(ls, off);
            inv[r] = 1.f / ls;
#pragma unroll
            for (int nf = 0; nf < 4; ++nf) {
                int a = nf * 16 + acol;
                if (a < AGENT)
                    pL[wave][kgrp * 4 + r][a] = (short)f2bf(sarr[nf]);
            }
        }

        short8v p0 = *reinterpret_cast<const short8v*>(&pL[wave][acol][kgrp * 8]);
        short8v p1 = *reinterpret_cast<const short8v*>(&pL[wave][acol][kgrp * 8 + 32]);

        f32x4 acco[4] = {};
#pragma unroll
        for (int nf = 0; nf < 4; ++nf) {
            acco[nf] = __builtin_amdgcn_mfma_f32_16x16x32_bf16(p0, bv[0][nf], acco[nf], 0, 0, 0);
            acco[nf] = __builtin_amdgcn_mfma_f32_16x16x32_bf16(p1, bv[1][nf], acco[nf], 0, 0, 0);
        }

#pragma unroll
        for (int r = 0; r < 4; ++r)
#pragma unroll
            for (int nf = 0; nf < 4; ++nf)
                oL[wave][kgrp * 4 + r][nf * 16 + acol] = acco[nf][r] * inv[r];

#pragma unroll
        for (int it2 = 0; it2 < 2; ++it2) {
            int item = lane + 64 * it2;       // 0..127
            int rl = item >> 3, d8 = item & 7;
            int n = n0 + rl;
            int i = n / WW, j = n % WW;
            float accv[8];
            {
                float4 o0 = *reinterpret_cast<const float4*>(&oL[wave][rl][d8 * 8]);
                float4 o1 = *reinterpret_cast<const float4*>(&oL[wave][rl][d8 * 8 + 4]);
                accv[0] = o0.x + cbS[d8 * 8 + 0]; accv[1] = o0.y + cbS[d8 * 8 + 1];
                accv[2] = o0.z + cbS[d8 * 8 + 2]; accv[3] = o0.w + cbS[d8 * 8 + 3];
                accv[4] = o1.x + cbS[d8 * 8 + 4]; accv[5] = o1.y + cbS[d8 * 8 + 5];
                accv[6] = o1.z + cbS[d8 * 8 + 6]; accv[7] = o1.w + cbS[d8 * 8 + 7];
            }
#pragma unroll
            for (int di = -1; di <= 1; ++di) {
                int ii = i + di;
                if (ii < 0 || ii >= HH) continue;
#pragma unroll
                for (int dj = -1; dj <= 1; ++dj) {
                    int jj = j + dj;
                    if (jj < 0 || jj >= WW) continue;
                    short8v vv = *reinterpret_cast<const short8v*>(
                        (const short*)kv_own + ((size_t)(b * NPOS + ii * WW + jj)) * (2 * DIM) + DIM + h * HD + d8 * 8);
                    int tap = (di + 1) * 3 + (dj + 1);
#pragma unroll
                    for (int u = 0; u < 8; ++u)
                        accv[u] += wS[tap][d8 * 8 + u] * bfs2f(vv[u]);
                }
            }
            short8v ov;
#pragma unroll
            for (int u = 0; u < 8; ++u) ov[u] = (short)f2bf(accv[u]);
            *reinterpret_cast<short8v*>((short*)qpre +
                ((size_t)(b * NPOS + n)) * DIM + h * HD + d8 * 8) = ov;
        }
    }
}

// ---------------------------------------------------------------------------
extern "C" void kernel_launch(void* const* d_in, const int* in_sizes, int n_in,
                              void* d_out, int out_size, void* d_ws, size_t ws_size,
                              hipStream_t stream)
{
    const float* rgb_fea    = (const float*)d_in[0];
    const float* depth_fea  = (const float*)d_in[1];
    const float* rgb_q_w    = (const float*)d_in[2];
    const float* rgb_kv_w   = (const float*)d_in[3];
    const float* rgb_proj_w = (const float*)d_in[4];
    const float* rgb_proj_b = (const float*)d_in[5];
    const float* depth_q_w    = (const float*)d_in[6];
    const float* depth_kv_w   = (const float*)d_in[7];
    const float* depth_proj_w = (const float*)d_in[8];
    const float* depth_proj_b = (const float*)d_in[9];
    const float* rgb_dwc_w   = (const float*)d_in[10];
    const float* rgb_dwc_b   = (const float*)d_in[11];
    const float* depth_dwc_w = (const float*)d_in[12];
    const float* depth_dwc_b = (const float*)d_in[13];
    const float* rgb_an   = (const float*)d_in[14];
    const float* rgb_na   = (const float*)d_in[15];
    const float* rgb_ah_b = (const float*)d_in[16];
    const float* rgb_aw_b = (const float*)d_in[17];
    const float* rgb_ha_b = (const float*)d_in[18];
    const float* rgb_wa_b = (const float*)d_in[19];
    const float* depth_an   = (const float*)d_in[20];
    const float* depth_na   = (const float*)d_in[21];
    const float* depth_ah_b = (const float*)d_in[22];
    const float* depth_aw_b = (const float*)d_in[23];
    const float* depth_ha_b = (const float*)d_in[24];
    const float* depth_wa_b = (const float*)d_in[25];

    char* ws = (char*)d_ws;
    size_t off = 0;
    auto alloc = [&](size_t bytes) -> void* {
        void* p = ws + off;
        off += (bytes + 255) & ~(size_t)255;
        return p;
    };
    bf16* rgb_q    = (bf16*)alloc((size_t)MROWS * DIM * 2);
    bf16* depth_q  = (bf16*)alloc((size_t)MROWS * DIM * 2);
    bf16* rgb_kv   = (bf16*)alloc((size_t)MROWS * 2 * DIM * 2);
    bf16* depth_kv = (bf16*)alloc((size_t)MROWS * 2 * DIM * 2);
    bf16* rgb_pb    = (bf16*)alloc((size_t)HEADS * AGENT * NPOS * 2);
    bf16* depth_pb  = (bf16*)alloc((size_t)HEADS * AGENT * NPOS * 2);
    bf16* rgb_ab    = (bf16*)alloc((size_t)HEADS * NPOS * AGENT * 2);
    bf16* depth_ab  = (bf16*)alloc((size_t)HEADS * NPOS * AGENT * 2);
    bf16* rgb_agv   = (bf16*)alloc((size_t)BATCH * HEADS * AGENT * HD * 2);
    bf16* depth_agv = (bf16*)alloc((size_t)BATCH * HEADS * AGENT * HD * 2);
    bf16* proj_wt_r = (bf16*)alloc((size_t)DIM * DIM * 2);
    bf16* proj_wt_d = (bf16*)alloc((size_t)DIM * DIM * 2);
    size_t ubase = off;
    bf16* q_wt_r  = (bf16*)alloc((size_t)DIM * DIM * 2);
    bf16* kv_wt_r = (bf16*)alloc((size_t)DIM * 2 * DIM * 2);
    bf16* q_wt_d  = (bf16*)alloc((size_t)DIM * DIM * 2);
    bf16* kv_wt_d = (bf16*)alloc((size_t)DIM * 2 * DIM * 2);
    off = ubase;  // alias
    float* rgb_ahp   = (float*)alloc((size_t)BATCH * AGENT * DIM * 4);
    float* depth_ahp = (float*)alloc((size_t)BATCH * AGENT * DIM * 4);

    // d_out doubles as scratch for the bf16-converted activations
    bf16* fea_bf_r = (bf16*)d_out;
    bf16* fea_bf_d = fea_bf_r + (size_t)MROWS * DIM;

    dim3 blk(256);
    int n8 = MROWS * DIM / 8;

    // 0) activation f32->bf16 + weight transposes (merged pairs)
    convert_bf16_2<<<(2 * n8 + 255) / 256, blk, 0, stream>>>(rgb_fea, fea_bf_r, depth_fea, fea_bf_d, n8);
    transpose_w_bf16_2<<<dim3(24, 48), blk, 0, stream>>>(rgb_q_w, q_wt_r, depth_q_w, q_wt_d, DIM, DIM);
    transpose_w_bf16_2<<<dim3(48, 48), blk, 0, stream>>>(rgb_kv_w, kv_wt_r, depth_kv_w, kv_wt_d, DIM, 2 * DIM);
    transpose_w_bf16_2<<<dim3(24, 48), blk, 0, stream>>>(rgb_proj_w, proj_wt_r, depth_proj_w, proj_wt_d, DIM, DIM);

    // 1) q / kv projections (merged rgb+depth per GEMM shape)
    gemm_mfma<false><<<dim3(6, 392), blk, 0, stream>>>(
        fea_bf_r, q_wt_r, nullptr, rgb_q,
        fea_bf_d, q_wt_d, nullptr, depth_q, MROWS, DIM, DIM);
    gemm_mfma<false><<<dim3(12, 392), blk, 0, stream>>>(
        fea_bf_r, kv_wt_r, nullptr, rgb_kv,
        fea_bf_d, kv_wt_d, nullptr, depth_kv, MROWS, 2 * DIM, DIM);

    // 2) agent pooling (merged)
    pool_kernel_2<<<(2 * BATCH * AGENT * DIM + 255) / 256, blk, 0, stream>>>(
        rgb_q, rgb_ahp, depth_q, depth_ahp);

    // 3) position biases (merged pairs)
    pos_bias_kernel_2<<<(2 * HEADS * AGENT * NPOS + 255) / 256, blk, 0, stream>>>(
        rgb_an, rgb_ah_b, rgb_aw_b, rgb_pb,
        depth_an, depth_ah_b, depth_aw_b, depth_pb);
    ag_bias_kernel_2<<<(2 * HEADS * NPOS * AGENT + 255) / 256, blk, 0, stream>>>(
        rgb_na, rgb_ha_b, rgb_wa_b, rgb_ab,
        depth_na, depth_ha_b, depth_wa_b, depth_ab);

    // 4) cross-modal agent aggregation (both modalities, one dispatch)
    agent_attn3<<<2 * BATCH * HEADS, blk, 0, stream>>>(
        depth_ahp, rgb_kv, rgb_pb, depth_agv,
        rgb_ahp, depth_kv, depth_pb, rgb_agv);

    // 5) agent broadcast + fused depthwise conv (both modalities, one dispatch)
    q_attn_mfma<<<2 * BATCH * HEADS * 2, blk, 0, stream>>>(
        rgb_q, rgb_kv, depth_ahp, depth_ab, depth_agv, rgb_dwc_w, rgb_dwc_b,
        depth_q, depth_kv, rgb_ahp, rgb_ab, rgb_agv, depth_dwc_w, depth_dwc_b);

    // 6) output projections (merged; overwrite d_out scratch with results)
    float* out = (float*)d_out;
    gemm_mfma<true><<<dim3(6, 392), blk, 0, stream>>>(
        rgb_q, proj_wt_r, rgb_proj_b, out,
        depth_q, proj_wt_d, depth_proj_b, out + (size_t)MROWS * DIM, MROWS, DIM, DIM);
}

// Round 14
// 683.377 us; speedup vs baseline: 1.1043x; 1.0199x over previous
//
#include <hip/hip_runtime.h>
#include <hip/hip_bf16.h>

#define BATCH 32
#define NPOS 784
#define DIM 768
#define HEADS 12
#define HD 64
#define AGENT 49
#define HH 28
#define WW 28
#define MROWS (BATCH*NPOS)   // 25088
#define SCALE 0.125f
#define CONV_CG 6            // channel groups of 128
#define CONV_IG 7            // image-row groups of 4

using bf16 = __hip_bfloat16;
typedef __attribute__((ext_vector_type(4))) float f32x4;
typedef __attribute__((ext_vector_type(8))) short short8v;

__device__ __forceinline__ float bf2f(bf16 x) { return __bfloat162float(x); }
__device__ __forceinline__ float bfs2f(short s) {
    unsigned int u = ((unsigned int)(unsigned short)s) << 16;
    return __uint_as_float(u);
}
__device__ __forceinline__ unsigned short f2bf(float x) {
    unsigned int u = __float_as_uint(x);
    unsigned int r = (u + 0x7fffu + ((u >> 16) & 1u)) >> 16;
    return (unsigned short)r;
}

// async global->LDS, 16B per lane (dest must be wave-uniform base + lane*16)
#define GLOAD_LDS16(g, l) __builtin_amdgcn_global_load_lds( \
    (const __attribute__((address_space(1))) unsigned int*)(g), \
    (__attribute__((address_space(3))) unsigned int*)(l), 16, 0, 0)

// ---------------------------------------------------------------------------
// f32 -> bf16 convert, two tensors in one dispatch
// ---------------------------------------------------------------------------
__global__ __launch_bounds__(256) void convert_bf16_2(
    const float* __restrict__ src0, bf16* __restrict__ dst0,
    const float* __restrict__ src1, bf16* __restrict__ dst1, int n8)
{
    int idx = blockIdx.x * 256 + threadIdx.x;
    if (idx >= 2 * n8) return;
    int sel = idx >= n8;
    int li = idx - sel * n8;
    const float* p = (sel ? src1 : src0) + (size_t)li * 8;
    float4 r0 = *reinterpret_cast<const float4*>(p);
    float4 r1 = *reinterpret_cast<const float4*>(p + 4);
    short8v v;
    v[0] = (short)f2bf(r0.x); v[1] = (short)f2bf(r0.y);
    v[2] = (short)f2bf(r0.z); v[3] = (short)f2bf(r0.w);
    v[4] = (short)f2bf(r1.x); v[5] = (short)f2bf(r1.y);
    v[6] = (short)f2bf(r1.z); v[7] = (short)f2bf(r1.w);
    *reinterpret_cast<short8v*>((short*)(sel ? dst1 : dst0) + (size_t)li * 8) = v;
}

// ---------------------------------------------------------------------------
// Transpose+convert pair: W [K][N] f32 -> Wt [N][K] bf16 (two weights/launch)
// ---------------------------------------------------------------------------
__global__ __launch_bounds__(256) void transpose_w_bf16_2(
    const float* __restrict__ W0, bf16* __restrict__ Wt0,
    const float* __restrict__ W1, bf16* __restrict__ Wt1, int K, int N)
{
    __shared__ float t[32][33];
    int gyh = gridDim.y >> 1;
    int sel = blockIdx.y >= gyh;
    const float* W = sel ? W1 : W0;
    bf16* Wt = sel ? Wt1 : Wt0;
    int tx = threadIdx.x & 31, ty = threadIdx.x >> 5;
    int k0 = (blockIdx.y - sel * gyh) * 32, n0 = blockIdx.x * 32;
#pragma unroll
    for (int i = 0; i < 4; ++i)
        t[ty + 8 * i][tx] = W[(size_t)(k0 + ty + 8 * i) * N + n0 + tx];
    __syncthreads();
#pragma unroll
    for (int i = 0; i < 4; ++i)
        Wt[(size_t)(n0 + ty + 8 * i) * K + k0 + tx] = __float2bfloat16(t[tx][ty + 8 * i]);
}

// ---------------------------------------------------------------------------
// MFMA GEMM (merged rgb+depth problems), R11 single-buffer structure.
// ---------------------------------------------------------------------------
template<bool OUTF32>
__global__ __launch_bounds__(256) void gemm_mfma(
    const bf16* __restrict__ A0, const bf16* __restrict__ Bt0,
    const float* __restrict__ bias0, void* __restrict__ Cp0,
    const bf16* __restrict__ A1, const bf16* __restrict__ Bt1,
    const float* __restrict__ bias1, void* __restrict__ Cp1,
    int M, int N, int K)
{
    __shared__ __align__(16) short As[128 * 64];
    __shared__ __align__(16) short Bs[128 * 64];

    int tid = threadIdx.x;
    int wave = tid >> 6, lane = tid & 63;

    int gx = gridDim.x;
    int gyh = gridDim.y >> 1;
    int nwg = gx * gridDim.y;
    int bid = blockIdx.y * gx + blockIdx.x;
    int cpx = nwg >> 3;
    int nb = (bid & 7) * cpx + (bid >> 3);
    int rowblk = nb / gx;
    int prob = rowblk >= gyh;
    int m0 = (rowblk - prob * gyh) * 128, n0 = (nb % gx) * 128;

    const short* Ab  = (const short*)(prob ? A1 : A0);
    const short* Btb = (const short*)(prob ? Bt1 : Bt0);
    const float* bias = prob ? bias1 : bias0;
    void* Cp = prob ? Cp1 : Cp0;

    int wm = (wave >> 1) * 64, wn = (wave & 1) * 64;
    int acol = lane & 15, kgrp = lane >> 4;

    f32x4 acc[4][4] = {};

    for (int k0 = 0; k0 < K; k0 += 64) {
#pragma unroll
        for (int it = 0; it < 4; ++it) {
            int idx = tid + 256 * it;
            int row = idx >> 3, seg = idx & 7;
            int sseg = seg ^ (row & 7);
            GLOAD_LDS16(Ab + (size_t)(m0 + row) * K + k0 + sseg * 8, &As[idx * 8]);
        }
#pragma unroll
        for (int it = 0; it < 4; ++it) {
            int idx = tid + 256 * it;
            int row = idx >> 3, seg = idx & 7;
            int sseg = seg ^ (row & 7);
            GLOAD_LDS16(Btb + (size_t)(n0 + row) * K + k0 + sseg * 8, &Bs[idx * 8]);
        }
        __syncthreads();

#pragma unroll
        for (int kk = 0; kk < 2; ++kk) {
            short8v af[4], bfr[4];
#pragma unroll
            for (int mf = 0; mf < 4; ++mf) {
                int row = wm + mf * 16 + acol;
                int seg = (kk * 4 + kgrp) ^ (row & 7);
                af[mf] = *reinterpret_cast<const short8v*>(&As[row * 64 + seg * 8]);
            }
#pragma unroll
            for (int nf = 0; nf < 4; ++nf) {
                int row = wn + nf * 16 + acol;
                int seg = (kk * 4 + kgrp) ^ (row & 7);
                bfr[nf] = *reinterpret_cast<const short8v*>(&Bs[row * 64 + seg * 8]);
            }
#pragma unroll
            for (int mf = 0; mf < 4; ++mf)
#pragma unroll
                for (int nf = 0; nf < 4; ++nf)
                    acc[mf][nf] = __builtin_amdgcn_mfma_f32_16x16x32_bf16(
                        af[mf], bfr[nf], acc[mf][nf], 0, 0, 0);
        }
        __syncthreads();
    }

    int rgrp = kgrp * 4, cidx = acol;
#pragma unroll
    for (int mf = 0; mf < 4; ++mf)
#pragma unroll
        for (int nf = 0; nf < 4; ++nf)
#pragma unroll
            for (int r = 0; r < 4; ++r) {
                int row = m0 + wm + mf * 16 + rgrp + r;
                int col = n0 + wn + nf * 16 + cidx;
                float v = acc[mf][nf][r];
                if constexpr (OUTF32)
                    ((float*)Cp)[(size_t)row * N + col] = v + bias[col];
                else
                    ((bf16*)Cp)[(size_t)row * N + col] = __float2bfloat16(v);
            }
}

// ---------------------------------------------------------------------------
// Pool pair
// ---------------------------------------------------------------------------
__global__ void pool_kernel_2(const bf16* __restrict__ q0, float* __restrict__ ahp0,
                              const bf16* __restrict__ q1, float* __restrict__ ahp1)
{
    int idx = blockIdx.x * 256 + threadIdx.x;
    int tot = BATCH * AGENT * DIM;
    if (idx >= 2 * tot) return;
    int sel = idx >= tot;
    int li = idx - sel * tot;
    const bf16* q = sel ? q1 : q0;
    float* ahp = sel ? ahp1 : ahp0;
    int c = li % DIM;
    int a = (li / DIM) % AGENT;
    int b = li / (DIM * AGENT);
    int ai = a / 7, aj = a % 7;
    float s = 0.f;
#pragma unroll
    for (int u = 0; u < 4; ++u)
#pragma unroll
        for (int v = 0; v < 4; ++v) {
            int n = (ai * 4 + u) * WW + (aj * 4 + v);
            s += bf2f(q[((size_t)b * NPOS + n) * DIM + c]);
        }
    ahp[li] = s * (1.f / 16.f);
}

// ---------------------------------------------------------------------------
// Bilinear 7->28 upsample helpers + bias kernels
// ---------------------------------------------------------------------------
__device__ __forceinline__ float bilerp7(const float* __restrict__ img, int i, int j)
{
    float si = 0.25f * i - 0.375f, sj = 0.25f * j - 0.375f;
    int i0 = (int)floorf(si); float fi = si - i0;
    int j0 = (int)floorf(sj); float fj = sj - j0;
    int i0c = min(max(i0, 0), 6), i1c = min(max(i0 + 1, 0), 6);
    int j0c = min(max(j0, 0), 6), j1c = min(max(j0 + 1, 0), 6);
    float v00 = img[i0c * 7 + j0c], v01 = img[i0c * 7 + j1c];
    float v10 = img[i1c * 7 + j0c], v11 = img[i1c * 7 + j1c];
    return (1.f - fi) * ((1.f - fj) * v00 + fj * v01) + fi * ((1.f - fj) * v10 + fj * v11);
}

__global__ void pos_bias_kernel_2(
    const float* __restrict__ an0, const float* __restrict__ ah_b0,
    const float* __restrict__ aw_b0, bf16* __restrict__ pb0,
    const float* __restrict__ an1, const float* __restrict__ ah_b1,
    const float* __restrict__ aw_b1, bf16* __restrict__ pb1)
{
    int idx = blockIdx.x * 256 + threadIdx.x;
    int tot = HEADS * AGENT * NPOS;
    if (idx >= 2 * tot) return;
    int sel = idx >= tot;
    int li = idx - sel * tot;
    const float* an = sel ? an1 : an0;
    const float* ah_b = sel ? ah_b1 : ah_b0;
    const float* aw_b = sel ? aw_b1 : aw_b0;
    bf16* pb = sel ? pb1 : pb0;
    int n = li % NPOS;
    int a = (li / NPOS) % AGENT;
    int h = li / (NPOS * AGENT);
    int i = n / WW, j = n % WW;
    float v = bilerp7(an + (size_t)(h * AGENT + a) * 49, i, j);
    v += ah_b[(h * AGENT + a) * HH + i] + aw_b[(h * AGENT + a) * WW + j];
    pb[li] = __float2bfloat16(v);
}

__global__ void ag_bias_kernel_2(
    const float* __restrict__ na0, const float* __restrict__ ha_b0,
    const float* __restrict__ wa_b0, bf16* __restrict__ ab0,
    const float* __restrict__ na1, const float* __restrict__ ha_b1,
    const float* __restrict__ wa_b1, bf16* __restrict__ ab1)
{
    int idx = blockIdx.x * 256 + threadIdx.x;
    int tot = HEADS * NPOS * AGENT;
    if (idx >= 2 * tot) return;
    int sel = idx >= tot;
    int li = idx - sel * tot;
    const float* na = sel ? na1 : na0;
    const float* ha_b = sel ? ha_b1 : ha_b0;
    const float* wa_b = sel ? wa_b1 : wa_b0;
    bf16* ab = sel ? ab1 : ab0;
    int a = li % AGENT;
    int n = (li / AGENT) % NPOS;
    int h = li / (AGENT * NPOS);
    int i = n / WW, j = n % WW;
    float v = bilerp7(na + (size_t)(h * AGENT + a) * 49, i, j);
    v += ha_b[(h * HH + i) * AGENT + a] + wa_b[(h * WW + j) * AGENT + a];
    ab[li] = __float2bfloat16(v);
}

// ---------------------------------------------------------------------------
// Agent attention v3 (full MFMA), both modalities in one dispatch. (unchanged)
// ---------------------------------------------------------------------------
__global__ __launch_bounds__(256, 2) void agent_attn3(
    const float* __restrict__ ahp0, const bf16* __restrict__ kv0,
    const bf16* __restrict__ pb0, bf16* __restrict__ agent_v0,
    const float* __restrict__ ahp1, const bf16* __restrict__ kv1,
    const bf16* __restrict__ pb1, bf16* __restrict__ agent_v1)
{
    __shared__ __align__(16) char smem[75776];
    short (*pL)[64][72]  = (short (*)[64][72])smem;
    short (*VtL)[64][72] = (short (*)[64][72])(smem + 36864);
    float (*Om)[64][66]  = (float (*)[64][66])smem;
    float (*mw)[64]      = (float (*)[64])(smem + 73728);
    float (*lw)[64]      = (float (*)[64])(smem + 74752);

    int sel = blockIdx.x >= BATCH * HEADS;
    int blk = blockIdx.x - sel * BATCH * HEADS;
    const float* ahp = sel ? ahp1 : ahp0;
    const bf16* kv = sel ? kv1 : kv0;
    const bf16* pb = sel ? pb1 : pb0;
    bf16* agent_v = sel ? agent_v1 : agent_v0;

    int tid = threadIdx.x;
    int wave = tid >> 6, lane = tid & 63;
    int acol = lane & 15, kgrp = lane >> 4;
    int h = blk % HEADS;
    int b = blk / HEADS;
    const short* kvs = (const short*)kv;
    const bf16* pbh = pb + (size_t)h * AGENT * NPOS;

    short8v qa[2][4];
#pragma unroll
    for (int ks = 0; ks < 2; ++ks)
#pragma unroll
        for (int mf = 0; mf < 4; ++mf) {
            int a = mf * 16 + acol;
            short8v v = {};
            if (a < AGENT) {
                const float* src = ahp + ((size_t)b * AGENT + a) * DIM + h * HD + ks * 32 + kgrp * 8;
                float4 r0 = *reinterpret_cast<const float4*>(src);
                float4 r1 = *reinterpret_cast<const float4*>(src + 4);
                v[0] = (short)f2bf(r0.x * SCALE); v[1] = (short)f2bf(r0.y * SCALE);
                v[2] = (short)f2bf(r0.z * SCALE); v[3] = (short)f2bf(r0.w * SCALE);
                v[4] = (short)f2bf(r1.x * SCALE); v[5] = (short)f2bf(r1.y * SCALE);
                v[6] = (short)f2bf(r1.z * SCALE); v[7] = (short)f2bf(r1.w * SCALE);
            }
            qa[ks][mf] = v;
        }

    float mrun[16], lrun[16];
#pragma unroll
    for (int i = 0; i < 16; ++i) { mrun[i] = -1e30f; lrun[i] = 0.f; }
    f32x4 accO[4][4] = {};

    for (int t = wave; t < 13; t += 4) {
        int n0 = t * 64;
        {
            int p = lane & 31, dh = lane >> 5;
            const short* v0p = kvs + (size_t)(b * NPOS + n0 + 2 * p) * (2 * DIM) + DIM + h * HD + dh * 32;
#pragma unroll
            for (int s = 0; s < 4; ++s) {
                short8v va = {}, vb = {};
                if (n0 + 2 * p < NPOS)     va = *reinterpret_cast<const short8v*>(v0p + s * 8);
                if (n0 + 2 * p + 1 < NPOS) vb = *reinterpret_cast<const short8v*>(v0p + 2 * DIM + s * 8);
#pragma unroll
                for (int u = 0; u < 8; ++u) {
                    int d = dh * 32 + s * 8 + u;
                    unsigned int w = ((unsigned int)(unsigned short)va[u]) |
                                     (((unsigned int)(unsigned short)vb[u]) << 16);
                    *reinterpret_cast<unsigned int*>(&VtL[wave][d][2 * p]) = w;
                }
            }
        }

        short8v kb[2][4];
#pragma unroll
        for (int nf = 0; nf < 4; ++nf) {
            int n = n0 + nf * 16 + acol;
            bool val = (n < NPOS);
            const short* kp = kvs + (size_t)(b * NPOS + n) * (2 * DIM) + h * HD + kgrp * 8;
#pragma unroll
            for (int ks = 0; ks < 2; ++ks) {
                short8v v = {};
                if (val) v = *reinterpret_cast<const short8v*>(kp + ks * 32);
                kb[ks][nf] = v;
            }
        }

        f32x4 accS[4][4] = {};
#pragma unroll
        for (int mf = 0; mf < 4; ++mf)
#pragma unroll
            for (int nf = 0; nf < 4; ++nf) {
                accS[mf][nf] = __builtin_amdgcn_mfma_f32_16x16x32_bf16(qa[0][mf], kb[0][nf], accS[mf][nf], 0, 0, 0);
                accS[mf][nf] = __builtin_amdgcn_mfma_f32_16x16x32_bf16(qa[1][mf], kb[1][nf], accS[mf][nf], 0, 0, 0);
            }

#pragma unroll
        for (int mf = 0; mf < 4; ++mf)
#pragma unroll
            for (int r = 0; r < 4; ++r) {
                int a = mf * 16 + kgrp * 4 + r;
                float s[4];
                float mt = -1e30f;
#pragma unroll
                for (int nf = 0; nf < 4; ++nf) {
                    int n = n0 + nf * 16 + acol;
                    float sv = -1e30f;
                    if (n < NPOS) {
                        sv = accS[mf][nf][r];
                        if (a < AGENT) sv += bf2f(pbh[(size_t)a * NPOS + n]);
                    }
                    s[nf] = sv;
                    mt = fmaxf(mt, sv);
                }
#pragma unroll
                for (int off = 1; off < 16; off <<= 1)
                    mt = fmaxf(mt, __shfl_xor(mt, off));
                float mnew = fmaxf(mrun[mf * 4 + r], mt);
                float fac = __expf(mrun[mf * 4 + r] - mnew);
                float ps = 0.f;
#pragma unroll
                for (int nf = 0; nf < 4; ++nf) {
                    float pv = (s[nf] > -1e29f) ? __expf(s[nf] - mnew) : 0.f;
                    ps += pv;
                    pL[wave][a][nf * 16 + acol] = (short)f2bf(pv);
                }
#pragma unroll
                for (int off = 1; off < 16; off <<= 1)
                    ps += __shfl_xor(ps, off);
                mrun[mf * 4 + r] = mnew;
                lrun[mf * 4 + r] = lrun[mf * 4 + r] * fac + ps;
#pragma unroll
                for (int df = 0; df < 4; ++df) accO[mf][df][r] *= fac;
            }

        short8v vb2[2][4];
#pragma unroll
        for (int ks = 0; ks < 2; ++ks)
#pragma unroll
            for (int df = 0; df < 4; ++df)
                vb2[ks][df] = *reinterpret_cast<const short8v*>(
                    &VtL[wave][df * 16 + acol][ks * 32 + kgrp * 8]);
#pragma unroll
        for (int mf = 0; mf < 4; ++mf) {
#pragma unroll
            for (int ks = 0; ks < 2; ++ks) {
                short8v pa = *reinterpret_cast<const short8v*>(
                    &pL[wave][mf * 16 + acol][ks * 32 + kgrp * 8]);
#pragma unroll
                for (int df = 0; df < 4; ++df)
                    accO[mf][df] = __builtin_amdgcn_mfma_f32_16x16x32_bf16(pa, vb2[ks][df], accO[mf][df], 0, 0, 0);
            }
        }
    }

    if (acol == 0) {
#pragma unroll
        for (int mf = 0; mf < 4; ++mf)
#pragma unroll
            for (int r = 0; r < 4; ++r) {
                mw[wave][mf * 16 + kgrp * 4 + r] = mrun[mf * 4 + r];
                lw[wave][mf * 16 + kgrp * 4 + r] = lrun[mf * 4 + r];
            }
    }
    __syncthreads();
#pragma unroll
    for (int mf = 0; mf < 4; ++mf)
#pragma unroll
        for (int df = 0; df < 4; ++df)
#pragma unroll
            for (int r = 0; r < 4; ++r)
                Om[wave][mf * 16 + kgrp * 4 + r][df * 16 + acol] = accO[mf][df][r];
    __syncthreads();

    for (int idx = tid; idx < AGENT * HD; idx += 256) {
        int a = idx >> 6, d = idx & 63;
        float m = fmaxf(fmaxf(mw[0][a], mw[1][a]), fmaxf(mw[2][a], mw[3][a]));
        float l = 0.f, o = 0.f;
#pragma unroll
        for (int w = 0; w < 4; ++w) {
            float f = __expf(mw[w][a] - m);
            l += f * lw[w][a];
            o += f * Om[w][a][d];
        }
        ((short*)agent_v)[(((size_t)b * HEADS + h) * AGENT + a) * HD + d] = (short)f2bf(o / l);
    }
}

// ---------------------------------------------------------------------------
// Q attention via MFMA (conv REMOVED -> separate dwc_kernel), in-place over q.
// ---------------------------------------------------------------------------
__global__ __launch_bounds__(256) void q_attn_mfma(
    bf16* qpre0, const float* __restrict__ ahp_x0, const bf16* __restrict__ ab_x0,
    const bf16* __restrict__ agv_x0,
    bf16* qpre1, const float* __restrict__ ahp_x1, const bf16* __restrict__ ab_x1,
    const bf16* __restrict__ agv_x1)
{
    __shared__ short pL[4][16][72];
    __shared__ float oL[4][16][68];

    int sel = blockIdx.x >= BATCH * HEADS * 2;
    int blk = blockIdx.x - sel * BATCH * HEADS * 2;
    bf16* qpre = sel ? qpre1 : qpre0;
    const float* ahp_x = sel ? ahp_x1 : ahp_x0;
    const bf16* ab_x = sel ? ab_x1 : ab_x0;
    const bf16* agv_x = sel ? agv_x1 : agv_x0;

    int half = blk & 1;
    int h = (blk >> 1) % HEADS;
    int b = blk / (2 * HEADS);
    int tid = threadIdx.x;
    int wave = tid >> 6, lane = tid & 63;
    int acol = lane & 15, kgrp = lane >> 4;

    for (int i = tid; i < 4 * 16 * 72; i += 256)
        ((short*)pL)[i] = 0;

    short8v bs[2][4];
#pragma unroll
    for (int ks = 0; ks < 2; ++ks)
#pragma unroll
        for (int nf = 0; nf < 4; ++nf) {
            int a = nf * 16 + acol;
            short8v v = {};
            if (a < AGENT) {
                const float* src = ahp_x + ((size_t)b * AGENT + a) * DIM + h * HD + ks * 32 + kgrp * 8;
                float4 r0 = *reinterpret_cast<const float4*>(src);
                float4 r1 = *reinterpret_cast<const float4*>(src + 4);
                v[0] = (short)f2bf(r0.x * SCALE); v[1] = (short)f2bf(r0.y * SCALE);
                v[2] = (short)f2bf(r0.z * SCALE); v[3] = (short)f2bf(r0.w * SCALE);
                v[4] = (short)f2bf(r1.x * SCALE); v[5] = (short)f2bf(r1.y * SCALE);
                v[6] = (short)f2bf(r1.z * SCALE); v[7] = (short)f2bf(r1.w * SCALE);
            }
            bs[ks][nf] = v;
        }

    const short* agvs = (const short*)agv_x;
    short8v bv[2][4];
#pragma unroll
    for (int ks = 0; ks < 2; ++ks)
#pragma unroll
        for (int nf = 0; nf < 4; ++nf) {
            int d = nf * 16 + acol;
            short8v v = {};
#pragma unroll
            for (int i = 0; i < 8; ++i) {
                int a = ks * 32 + kgrp * 8 + i;
                if (a < AGENT)
                    v[i] = agvs[(((size_t)b * HEADS + h) * AGENT + a) * HD + d];
            }
            bv[ks][nf] = v;
        }

    __syncthreads();

    int tstart = half ? 25 : 0, tend = half ? 49 : 25;
    for (int t = tstart + wave; t < tend; t += 4) {
        int n0 = t * 16;
        const short* qrow = (const short*)qpre +
            ((size_t)(b * NPOS + n0 + acol)) * DIM + h * HD + kgrp * 8;
        short8v a0 = *reinterpret_cast<const short8v*>(qrow);
        short8v a1 = *reinterpret_cast<const short8v*>(qrow + 32);

        f32x4 accs[4] = {};
#pragma unroll
        for (int nf = 0; nf < 4; ++nf) {
            accs[nf] = __builtin_amdgcn_mfma_f32_16x16x32_bf16(a0, bs[0][nf], accs[nf], 0, 0, 0);
            accs[nf] = __builtin_amdgcn_mfma_f32_16x16x32_bf16(a1, bs[1][nf], accs[nf], 0, 0, 0);
        }

        float inv[4];
#pragma unroll
        for (int r = 0; r < 4; ++r) {
            int n = n0 + kgrp * 4 + r;
            float sarr[4];
            float m = -1e30f;
#pragma unroll
            for (int nf = 0; nf < 4; ++nf) {
                int a = nf * 16 + acol;
                float s = -1e30f;
                if (a < AGENT)
                    s = accs[nf][r] + bf2f(ab_x[((size_t)h * NPOS + n) * AGENT + a]);
                sarr[nf] = s;
                m = fmaxf(m, s);
            }
#pragma unroll
            for (int off = 1; off < 16; off <<= 1)
                m = fmaxf(m, __shfl_xor(m, off));
            float ls = 0.f;
#pragma unroll
            for (int nf = 0; nf < 4; ++nf) {
                float p = (sarr[nf] > -1e29f) ? __expf(sarr[nf] - m) : 0.f;
                sarr[nf] = p;
                ls += p;
            }
#pragma unroll
            for (int off = 1; off < 16; off <<= 1)
                ls += __shfl_xor(ls, off);
            inv[r] = 1.f / ls;
#pragma unroll
            for (int nf = 0; nf < 4; ++nf) {
                int a = nf * 16 + acol;
                if (a < AGENT)
                    pL[wave][kgrp * 4 + r][a] = (short)f2bf(sarr[nf]);
            }
        }

        short8v p0 = *reinterpret_cast<const short8v*>(&pL[wave][acol][kgrp * 8]);
        short8v p1 = *reinterpret_cast<const short8v*>(&pL[wave][acol][kgrp * 8 + 32]);

        f32x4 acco[4] = {};
#pragma unroll
        for (int nf = 0; nf < 4; ++nf) {
            acco[nf] = __builtin_amdgcn_mfma_f32_16x16x32_bf16(p0, bv[0][nf], acco[nf], 0, 0, 0);
            acco[nf] = __builtin_amdgcn_mfma_f32_16x16x32_bf16(p1, bv[1][nf], acco[nf], 0, 0, 0);
        }

#pragma unroll
        for (int r = 0; r < 4; ++r)
#pragma unroll
            for (int nf = 0; nf < 4; ++nf)
                oL[wave][kgrp * 4 + r][nf * 16 + acol] = acco[nf][r] * inv[r];

        // vectorized store of attention output
#pragma unroll
        for (int it2 = 0; it2 < 2; ++it2) {
            int item = lane + 64 * it2;       // 0..127
            int rl = item >> 3, d8 = item & 7;
            int n = n0 + rl;
            float4 o0 = *reinterpret_cast<const float4*>(&oL[wave][rl][d8 * 8]);
            float4 o1 = *reinterpret_cast<const float4*>(&oL[wave][rl][d8 * 8 + 4]);
            short8v ov;
            ov[0] = (short)f2bf(o0.x); ov[1] = (short)f2bf(o0.y);
            ov[2] = (short)f2bf(o0.z); ov[3] = (short)f2bf(o0.w);
            ov[4] = (short)f2bf(o1.x); ov[5] = (short)f2bf(o1.y);
            ov[6] = (short)f2bf(o1.z); ov[7] = (short)f2bf(o1.w);
            *reinterpret_cast<short8v*>((short*)qpre +
                ((size_t)(b * NPOS + n)) * DIM + h * HD + d8 * 8) = ov;
        }
    }
}

// ---------------------------------------------------------------------------
// Depthwise 3x3 conv, LDS-tiled: pre += conv(V) + bias. Both modalities.
// block = (modality, b, cg of 128 ch, ig of 4 image rows); V halo (6 rows x
// 28 cols x 128 ch) staged once in LDS (stride 136 -> conflict-free taps).
// ---------------------------------------------------------------------------
__global__ __launch_bounds__(256) void dwc_kernel(
    bf16* pre0, const bf16* __restrict__ kv0,
    const float* __restrict__ w0, const float* __restrict__ b0,
    bf16* pre1, const bf16* __restrict__ kv1,
    const float* __restrict__ w1, const float* __restrict__ b1)
{
    __shared__ __align__(16) short Vs[168][136];   // [6*28 pos][128 ch pad]
    __shared__ float wS[9][128];
    __shared__ float cbS[128];

    int blk = blockIdx.x;
    int per = BATCH * CONV_CG * CONV_IG;
    int sel = blk >= per;
    blk -= sel * per;
    bf16* pre = sel ? pre1 : pre0;
    const short* kvs = (const short*)(sel ? kv1 : kv0);
    const float* dw = sel ? w1 : w0;
    const float* db = sel ? b1 : b0;

    int ig = blk % CONV_IG;
    int cg = (blk / CONV_IG) % CONV_CG;
    int b  = blk / (CONV_IG * CONV_CG);
    int c0 = cg * 128;
    int tid = threadIdx.x;

    for (int i = tid; i < 9 * 128; i += 256)
        wS[i >> 7][i & 127] = dw[(i >> 7) * DIM + c0 + (i & 127)];
    if (tid < 128) cbS[tid] = db[c0 + tid];

    // stage V rows ig*4-1 .. ig*4+4 (zeros for OOB rows)
    for (int it = 0; it < 11; ++it) {
        int item = tid + 256 * it;
        if (item >= 168 * 16) break;
        int pos = item >> 4, c8 = item & 15;
        int ii = pos / 28, jj = pos % 28;
        int irow = ig * 4 - 1 + ii;
        short8v v = {};
        if (irow >= 0 && irow < HH)
            v = *reinterpret_cast<const short8v*>(
                kvs + (size_t)(b * NPOS + irow * WW + jj) * (2 * DIM) + DIM + c0 + c8 * 8);
        *reinterpret_cast<short8v*>(&Vs[pos][c8 * 8]) = v;
    }
    __syncthreads();

    // compute 4 rows x 28 cols x 128 ch = 1792 items (7 per thread)
#pragma unroll
    for (int it = 0; it < 7; ++it) {
        int item = tid + 256 * it;
        int opos = item >> 4, c8 = item & 15;
        int oi = opos / 28, oj = opos % 28;
        int n = (ig * 4 + oi) * WW + oj;
        short* pp = (short*)pre + (size_t)(b * NPOS + n) * DIM + c0 + c8 * 8;
        short8v pv = *reinterpret_cast<const short8v*>(pp);
        float acc[8];
#pragma unroll
        for (int u = 0; u < 8; ++u) acc[u] = bfs2f(pv[u]) + cbS[c8 * 8 + u];
#pragma unroll
        for (int di = -1; di <= 1; ++di) {
#pragma unroll
            for (int dj = -1; dj <= 1; ++dj) {
                int jj = oj + dj;
                if (jj < 0 || jj >= WW) continue;
                int pos = (oi + 1 + di) * 28 + jj;
                short8v vv = *reinterpret_cast<const short8v*>(&Vs[pos][c8 * 8]);
                int tap = (di + 1) * 3 + (dj + 1);
#pragma unroll
                for (int u = 0; u < 8; ++u)
                    acc[u] += wS[tap][c8 * 8 + u] * bfs2f(vv[u]);
            }
        }
        short8v ov;
#pragma unroll
        for (int u = 0; u < 8; ++u) ov[u] = (short)f2bf(acc[u]);
        *reinterpret_cast<short8v*>(pp) = ov;
    }
}

// ---------------------------------------------------------------------------
extern "C" void kernel_launch(void* const* d_in, const int* in_sizes, int n_in,
                              void* d_out, int out_size, void* d_ws, size_t ws_size,
                              hipStream_t stream)
{
    const float* rgb_fea    = (const float*)d_in[0];
    const float* depth_fea  = (const float*)d_in[1];
    const float* rgb_q_w    = (const float*)d_in[2];
    const float* rgb_kv_w   = (const float*)d_in[3];
    const float* rgb_proj_w = (const float*)d_in[4];
    const float* rgb_proj_b = (const float*)d_in[5];
    const float* depth_q_w    = (const float*)d_in[6];
    const float* depth_kv_w   = (const float*)d_in[7];
    const float* depth_proj_w = (const float*)d_in[8];
    const float* depth_proj_b = (const float*)d_in[9];
    const float* rgb_dwc_w   = (const float*)d_in[10];
    const float* rgb_dwc_b   = (const float*)d_in[11];
    const float* depth_dwc_w = (const float*)d_in[12];
    const float* depth_dwc_b = (const float*)d_in[13];
    const float* rgb_an   = (const float*)d_in[14];
    const float* rgb_na   = (const float*)d_in[15];
    const float* rgb_ah_b = (const float*)d_in[16];
    const float* rgb_aw_b = (const float*)d_in[17];
    const float* rgb_ha_b = (const float*)d_in[18];
    const float* rgb_wa_b = (const float*)d_in[19];
    const float* depth_an   = (const float*)d_in[20];
    const float* depth_na   = (const float*)d_in[21];
    const float* depth_ah_b = (const float*)d_in[22];
    const float* depth_aw_b = (const float*)d_in[23];
    const float* depth_ha_b = (const float*)d_in[24];
    const float* depth_wa_b = (const float*)d_in[25];

    char* ws = (char*)d_ws;
    size_t off = 0;
    auto alloc = [&](size_t bytes) -> void* {
        void* p = ws + off;
        off += (bytes + 255) & ~(size_t)255;
        return p;
    };
    bf16* rgb_q    = (bf16*)alloc((size_t)MROWS * DIM * 2);
    bf16* depth_q  = (bf16*)alloc((size_t)MROWS * DIM * 2);
    bf16* rgb_kv   = (bf16*)alloc((size_t)MROWS * 2 * DIM * 2);
    bf16* depth_kv = (bf16*)alloc((size_t)MROWS * 2 * DIM * 2);
    bf16* rgb_pb    = (bf16*)alloc((size_t)HEADS * AGENT * NPOS * 2);
    bf16* depth_pb  = (bf16*)alloc((size_t)HEADS * AGENT * NPOS * 2);
    bf16* rgb_ab    = (bf16*)alloc((size_t)HEADS * NPOS * AGENT * 2);
    bf16* depth_ab  = (bf16*)alloc((size_t)HEADS * NPOS * AGENT * 2);
    bf16* rgb_agv   = (bf16*)alloc((size_t)BATCH * HEADS * AGENT * HD * 2);
    bf16* depth_agv = (bf16*)alloc((size_t)BATCH * HEADS * AGENT * HD * 2);
    bf16* proj_wt_r = (bf16*)alloc((size_t)DIM * DIM * 2);
    bf16* proj_wt_d = (bf16*)alloc((size_t)DIM * DIM * 2);
    size_t ubase = off;
    bf16* q_wt_r  = (bf16*)alloc((size_t)DIM * DIM * 2);
    bf16* kv_wt_r = (bf16*)alloc((size_t)DIM * 2 * DIM * 2);
    bf16* q_wt_d  = (bf16*)alloc((size_t)DIM * DIM * 2);
    bf16* kv_wt_d = (bf16*)alloc((size_t)DIM * 2 * DIM * 2);
    off = ubase;  // alias
    float* rgb_ahp   = (float*)alloc((size_t)BATCH * AGENT * DIM * 4);
    float* depth_ahp = (float*)alloc((size_t)BATCH * AGENT * DIM * 4);

    // d_out doubles as scratch for the bf16-converted activations
    bf16* fea_bf_r = (bf16*)d_out;
    bf16* fea_bf_d = fea_bf_r + (size_t)MROWS * DIM;

    dim3 blk(256);
    int n8 = MROWS * DIM / 8;

    // 0) activation f32->bf16 + weight transposes (merged pairs)
    convert_bf16_2<<<(2 * n8 + 255) / 256, blk, 0, stream>>>(rgb_fea, fea_bf_r, depth_fea, fea_bf_d, n8);
    transpose_w_bf16_2<<<dim3(24, 48), blk, 0, stream>>>(rgb_q_w, q_wt_r, depth_q_w, q_wt_d, DIM, DIM);
    transpose_w_bf16_2<<<dim3(48, 48), blk, 0, stream>>>(rgb_kv_w, kv_wt_r, depth_kv_w, kv_wt_d, DIM, 2 * DIM);
    transpose_w_bf16_2<<<dim3(24, 48), blk, 0, stream>>>(rgb_proj_w, proj_wt_r, depth_proj_w, proj_wt_d, DIM, DIM);

    // 1) q / kv projections (merged rgb+depth per GEMM shape)
    gemm_mfma<false><<<dim3(6, 392), blk, 0, stream>>>(
        fea_bf_r, q_wt_r, nullptr, rgb_q,
        fea_bf_d, q_wt_d, nullptr, depth_q, MROWS, DIM, DIM);
    gemm_mfma<false><<<dim3(12, 392), blk, 0, stream>>>(
        fea_bf_r, kv_wt_r, nullptr, rgb_kv,
        fea_bf_d, kv_wt_d, nullptr, depth_kv, MROWS, 2 * DIM, DIM);

    // 2) agent pooling (merged)
    pool_kernel_2<<<(2 * BATCH * AGENT * DIM + 255) / 256, blk, 0, stream>>>(
        rgb_q, rgb_ahp, depth_q, depth_ahp);

    // 3) position biases (merged pairs)
    pos_bias_kernel_2<<<(2 * HEADS * AGENT * NPOS + 255) / 256, blk, 0, stream>>>(
        rgb_an, rgb_ah_b, rgb_aw_b, rgb_pb,
        depth_an, depth_ah_b, depth_aw_b, depth_pb);
    ag_bias_kernel_2<<<(2 * HEADS * NPOS * AGENT + 255) / 256, blk, 0, stream>>>(
        rgb_na, rgb_ha_b, rgb_wa_b, rgb_ab,
        depth_na, depth_ha_b, depth_wa_b, depth_ab);

    // 4) cross-modal agent aggregation (both modalities, one dispatch)
    agent_attn3<<<2 * BATCH * HEADS, blk, 0, stream>>>(
        depth_ahp, rgb_kv, rgb_pb, depth_agv,
        rgb_ahp, depth_kv, depth_pb, rgb_agv);

    // 5) agent broadcast (in-place q -> attention output)
    q_attn_mfma<<<2 * BATCH * HEADS * 2, blk, 0, stream>>>(
        rgb_q, depth_ahp, depth_ab, depth_agv,
        depth_q, rgb_ahp, rgb_ab, rgb_agv);

    // 5b) depthwise conv added in (LDS-tiled, both modalities)
    dwc_kernel<<<2 * BATCH * CONV_CG * CONV_IG, blk, 0, stream>>>(
        rgb_q, rgb_kv, rgb_dwc_w, rgb_dwc_b,
        depth_q, depth_kv, depth_dwc_w, depth_dwc_b);

    // 6) output projections (merged; overwrite d_out scratch with results)
    float* out = (float*)d_out;
    gemm_mfma<true><<<dim3(6, 392), blk, 0, stream>>>(
        rgb_q, proj_wt_r, rgb_proj_b, out,
        depth_q, proj_wt_d, depth_proj_b, out + (size_t)MROWS * DIM, MROWS, DIM, DIM);
}

// Round 15
// 636.469 us; speedup vs baseline: 1.1857x; 1.0737x over previous
//
#include <hip/hip_runtime.h>
#include <hip/hip_bf16.h>

#define BATCH 32
#define NPOS 784
#define DIM 768
#define HEADS 12
#define HD 64
#define AGENT 49
#define HH 28
#define WW 28
#define MROWS (BATCH*NPOS)   // 25088
#define SCALE 0.125f
#define CONV_CG 6
#define CONV_IG 7

using bf16 = __hip_bfloat16;
typedef __attribute__((ext_vector_type(4))) float f32x4;
typedef __attribute__((ext_vector_type(8))) short short8v;

__device__ __forceinline__ float bf2f(bf16 x) { return __bfloat162float(x); }
__device__ __forceinline__ float bfs2f(short s) {
    unsigned int u = ((unsigned int)(unsigned short)s) << 16;
    return __uint_as_float(u);
}
__device__ __forceinline__ unsigned short f2bf(float x) {
    unsigned int u = __float_as_uint(x);
    unsigned int r = (u + 0x7fffu + ((u >> 16) & 1u)) >> 16;
    return (unsigned short)r;
}

#define GLOAD_LDS16(g, l) __builtin_amdgcn_global_load_lds( \
    (const __attribute__((address_space(1))) unsigned int*)(g), \
    (__attribute__((address_space(3))) unsigned int*)(l), 16, 0, 0)

// ---------------------------------------------------------------------------
// f32 -> bf16 convert, two tensors in one dispatch
// ---------------------------------------------------------------------------
__global__ __launch_bounds__(256) void convert_bf16_2(
    const float* __restrict__ src0, bf16* __restrict__ dst0,
    const float* __restrict__ src1, bf16* __restrict__ dst1, int n8)
{
    int idx = blockIdx.x * 256 + threadIdx.x;
    if (idx >= 2 * n8) return;
    int sel = idx >= n8;
    int li = idx - sel * n8;
    const float* p = (sel ? src1 : src0) + (size_t)li * 8;
    float4 r0 = *reinterpret_cast<const float4*>(p);
    float4 r1 = *reinterpret_cast<const float4*>(p + 4);
    short8v v;
    v[0] = (short)f2bf(r0.x); v[1] = (short)f2bf(r0.y);
    v[2] = (short)f2bf(r0.z); v[3] = (short)f2bf(r0.w);
    v[4] = (short)f2bf(r1.x); v[5] = (short)f2bf(r1.y);
    v[6] = (short)f2bf(r1.z); v[7] = (short)f2bf(r1.w);
    *reinterpret_cast<short8v*>((short*)(sel ? dst1 : dst0) + (size_t)li * 8) = v;
}

// ---------------------------------------------------------------------------
// Transpose+convert pair: W [K][N] f32 -> Wt [N][K] bf16
// ---------------------------------------------------------------------------
__global__ __launch_bounds__(256) void transpose_w_bf16_2(
    const float* __restrict__ W0, bf16* __restrict__ Wt0,
    const float* __restrict__ W1, bf16* __restrict__ Wt1, int K, int N)
{
    __shared__ float t[32][33];
    int gyh = gridDim.y >> 1;
    int sel = blockIdx.y >= gyh;
    const float* W = sel ? W1 : W0;
    bf16* Wt = sel ? Wt1 : Wt0;
    int tx = threadIdx.x & 31, ty = threadIdx.x >> 5;
    int k0 = (blockIdx.y - sel * gyh) * 32, n0 = blockIdx.x * 32;
#pragma unroll
    for (int i = 0; i < 4; ++i)
        t[ty + 8 * i][tx] = W[(size_t)(k0 + ty + 8 * i) * N + n0 + tx];
    __syncthreads();
#pragma unroll
    for (int i = 0; i < 4; ++i)
        Wt[(size_t)(n0 + ty + 8 * i) * K + k0 + tx] = __float2bfloat16(t[tx][ty + 8 * i]);
}

// ---------------------------------------------------------------------------
// MFMA GEMM (merged rgb+depth; optional N-split routing to two C buffers):
// col-tile < nsplit -> CpA (row stride nsplit), else CpB (stride N-nsplit).
// 128x128 tile, BK=64, global_load_lds w16, XOR-swizzled LDS, bijective XCD
// grid swizzle. __launch_bounds__(256,4): occupancy floor (VGPR<=128 cap OK).
// ---------------------------------------------------------------------------
template<bool OUTF32>
__global__ __launch_bounds__(256, 4) void gemm_mfma(
    const bf16* __restrict__ A0, const bf16* __restrict__ Bt0,
    const float* __restrict__ bias0, void* __restrict__ CpA0, void* __restrict__ CpB0,
    const bf16* __restrict__ A1, const bf16* __restrict__ Bt1,
    const float* __restrict__ bias1, void* __restrict__ CpA1, void* __restrict__ CpB1,
    int M, int N, int K, int nsplit)
{
    __shared__ __align__(16) short As[128 * 64];
    __shared__ __align__(16) short Bs[128 * 64];

    int tid = threadIdx.x;
    int wave = tid >> 6, lane = tid & 63;

    int gx = gridDim.x;
    int gyh = gridDim.y >> 1;
    int nwg = gx * gridDim.y;
    int bid = blockIdx.y * gx + blockIdx.x;
    int cpx = nwg >> 3;
    int nb = (bid & 7) * cpx + (bid >> 3);
    int rowblk = nb / gx;
    int prob = rowblk >= gyh;
    int m0 = (rowblk - prob * gyh) * 128, n0 = (nb % gx) * 128;

    const short* Ab  = (const short*)(prob ? A1 : A0);
    const short* Btb = (const short*)(prob ? Bt1 : Bt0);
    const float* bias = prob ? bias1 : bias0;

    // column-split C routing (uniform per block)
    void* Cp; int Ns; int cb;
    if (nsplit > 0 && n0 >= nsplit) {
        Cp = prob ? CpB1 : CpB0; Ns = N - nsplit; cb = n0 - nsplit;
    } else {
        Cp = prob ? CpA1 : CpA0; Ns = (nsplit > 0) ? nsplit : N; cb = n0;
    }

    int wm = (wave >> 1) * 64, wn = (wave & 1) * 64;
    int acol = lane & 15, kgrp = lane >> 4;

    f32x4 acc[4][4] = {};

    for (int k0 = 0; k0 < K; k0 += 64) {
#pragma unroll
        for (int it = 0; it < 4; ++it) {
            int idx = tid + 256 * it;
            int row = idx >> 3, seg = idx & 7;
            int sseg = seg ^ (row & 7);
            GLOAD_LDS16(Ab + (size_t)(m0 + row) * K + k0 + sseg * 8, &As[idx * 8]);
        }
#pragma unroll
        for (int it = 0; it < 4; ++it) {
            int idx = tid + 256 * it;
            int row = idx >> 3, seg = idx & 7;
            int sseg = seg ^ (row & 7);
            GLOAD_LDS16(Btb + (size_t)(n0 + row) * K + k0 + sseg * 8, &Bs[idx * 8]);
        }
        __syncthreads();

#pragma unroll
        for (int kk = 0; kk < 2; ++kk) {
            short8v af[4], bfr[4];
#pragma unroll
            for (int mf = 0; mf < 4; ++mf) {
                int row = wm + mf * 16 + acol;
                int seg = (kk * 4 + kgrp) ^ (row & 7);
                af[mf] = *reinterpret_cast<const short8v*>(&As[row * 64 + seg * 8]);
            }
#pragma unroll
            for (int nf = 0; nf < 4; ++nf) {
                int row = wn + nf * 16 + acol;
                int seg = (kk * 4 + kgrp) ^ (row & 7);
                bfr[nf] = *reinterpret_cast<const short8v*>(&Bs[row * 64 + seg * 8]);
            }
#pragma unroll
            for (int mf = 0; mf < 4; ++mf)
#pragma unroll
                for (int nf = 0; nf < 4; ++nf)
                    acc[mf][nf] = __builtin_amdgcn_mfma_f32_16x16x32_bf16(
                        af[mf], bfr[nf], acc[mf][nf], 0, 0, 0);
        }
        __syncthreads();
    }

    int rgrp = kgrp * 4, cidx = acol;
#pragma unroll
    for (int mf = 0; mf < 4; ++mf)
#pragma unroll
        for (int nf = 0; nf < 4; ++nf)
#pragma unroll
            for (int r = 0; r < 4; ++r) {
                int row = m0 + wm + mf * 16 + rgrp + r;
                int col = cb + wn + nf * 16 + cidx;
                float v = acc[mf][nf][r];
                if constexpr (OUTF32)
                    ((float*)Cp)[(size_t)row * Ns + col] = v + bias[col];
                else
                    ((bf16*)Cp)[(size_t)row * Ns + col] = __float2bfloat16(v);
            }
}

// ---------------------------------------------------------------------------
// Pool pair
// ---------------------------------------------------------------------------
__global__ void pool_kernel_2(const bf16* __restrict__ q0, float* __restrict__ ahp0,
                              const bf16* __restrict__ q1, float* __restrict__ ahp1)
{
    int idx = blockIdx.x * 256 + threadIdx.x;
    int tot = BATCH * AGENT * DIM;
    if (idx >= 2 * tot) return;
    int sel = idx >= tot;
    int li = idx - sel * tot;
    const bf16* q = sel ? q1 : q0;
    float* ahp = sel ? ahp1 : ahp0;
    int c = li % DIM;
    int a = (li / DIM) % AGENT;
    int b = li / (DIM * AGENT);
    int ai = a / 7, aj = a % 7;
    float s = 0.f;
#pragma unroll
    for (int u = 0; u < 4; ++u)
#pragma unroll
        for (int v = 0; v < 4; ++v) {
            int n = (ai * 4 + u) * WW + (aj * 4 + v);
            s += bf2f(q[((size_t)b * NPOS + n) * DIM + c]);
        }
    ahp[li] = s * (1.f / 16.f);
}

// ---------------------------------------------------------------------------
// Bilinear 7->28 upsample helpers + bias kernels
// ---------------------------------------------------------------------------
__device__ __forceinline__ float bilerp7(const float* __restrict__ img, int i, int j)
{
    float si = 0.25f * i - 0.375f, sj = 0.25f * j - 0.375f;
    int i0 = (int)floorf(si); float fi = si - i0;
    int j0 = (int)floorf(sj); float fj = sj - j0;
    int i0c = min(max(i0, 0), 6), i1c = min(max(i0 + 1, 0), 6);
    int j0c = min(max(j0, 0), 6), j1c = min(max(j0 + 1, 0), 6);
    float v00 = img[i0c * 7 + j0c], v01 = img[i0c * 7 + j1c];
    float v10 = img[i1c * 7 + j0c], v11 = img[i1c * 7 + j1c];
    return (1.f - fi) * ((1.f - fj) * v00 + fj * v01) + fi * ((1.f - fj) * v10 + fj * v11);
}

__global__ void pos_bias_kernel_2(
    const float* __restrict__ an0, const float* __restrict__ ah_b0,
    const float* __restrict__ aw_b0, bf16* __restrict__ pb0,
    const float* __restrict__ an1, const float* __restrict__ ah_b1,
    const float* __restrict__ aw_b1, bf16* __restrict__ pb1)
{
    int idx = blockIdx.x * 256 + threadIdx.x;
    int tot = HEADS * AGENT * NPOS;
    if (idx >= 2 * tot) return;
    int sel = idx >= tot;
    int li = idx - sel * tot;
    const float* an = sel ? an1 : an0;
    const float* ah_b = sel ? ah_b1 : ah_b0;
    const float* aw_b = sel ? aw_b1 : aw_b0;
    bf16* pb = sel ? pb1 : pb0;
    int n = li % NPOS;
    int a = (li / NPOS) % AGENT;
    int h = li / (NPOS * AGENT);
    int i = n / WW, j = n % WW;
    float v = bilerp7(an + (size_t)(h * AGENT + a) * 49, i, j);
    v += ah_b[(h * AGENT + a) * HH + i] + aw_b[(h * AGENT + a) * WW + j];
    pb[li] = __float2bfloat16(v);
}

__global__ void ag_bias_kernel_2(
    const float* __restrict__ na0, const float* __restrict__ ha_b0,
    const float* __restrict__ wa_b0, bf16* __restrict__ ab0,
    const float* __restrict__ na1, const float* __restrict__ ha_b1,
    const float* __restrict__ wa_b1, bf16* __restrict__ ab1)
{
    int idx = blockIdx.x * 256 + threadIdx.x;
    int tot = HEADS * NPOS * AGENT;
    if (idx >= 2 * tot) return;
    int sel = idx >= tot;
    int li = idx - sel * tot;
    const float* na = sel ? na1 : na0;
    const float* ha_b = sel ? ha_b1 : ha_b0;
    const float* wa_b = sel ? wa_b1 : wa_b0;
    bf16* ab = sel ? ab1 : ab0;
    int a = li % AGENT;
    int n = (li / AGENT) % NPOS;
    int h = li / (AGENT * NPOS);
    int i = n / WW, j = n % WW;
    float v = bilerp7(na + (size_t)(h * AGENT + a) * 49, i, j);
    v += ha_b[(h * HH + i) * AGENT + a] + wa_b[(h * WW + j) * AGENT + a];
    ab[li] = __float2bfloat16(v);
}

// ---------------------------------------------------------------------------
// Agent attention v3 (full MFMA), both modalities in one dispatch.
// ---------------------------------------------------------------------------
__global__ __launch_bounds__(256, 2) void agent_attn3(
    const float* __restrict__ ahp0, const bf16* __restrict__ kv0,
    const bf16* __restrict__ pb0, bf16* __restrict__ agent_v0,
    const float* __restrict__ ahp1, const bf16* __restrict__ kv1,
    const bf16* __restrict__ pb1, bf16* __restrict__ agent_v1)
{
    __shared__ __align__(16) char smem[75776];
    short (*pL)[64][72]  = (short (*)[64][72])smem;
    short (*VtL)[64][72] = (short (*)[64][72])(smem + 36864);
    float (*Om)[64][66]  = (float (*)[64][66])smem;
    float (*mw)[64]      = (float (*)[64])(smem + 73728);
    float (*lw)[64]      = (float (*)[64])(smem + 74752);

    int sel = blockIdx.x >= BATCH * HEADS;
    int blk = blockIdx.x - sel * BATCH * HEADS;
    const float* ahp = sel ? ahp1 : ahp0;
    const bf16* kv = sel ? kv1 : kv0;
    const bf16* pb = sel ? pb1 : pb0;
    bf16* agent_v = sel ? agent_v1 : agent_v0;

    int tid = threadIdx.x;
    int wave = tid >> 6, lane = tid & 63;
    int acol = lane & 15, kgrp = lane >> 4;
    int h = blk % HEADS;
    int b = blk / HEADS;
    const short* kvs = (const short*)kv;
    const bf16* pbh = pb + (size_t)h * AGENT * NPOS;

    short8v qa[2][4];
#pragma unroll
    for (int ks = 0; ks < 2; ++ks)
#pragma unroll
        for (int mf = 0; mf < 4; ++mf) {
            int a = mf * 16 + acol;
            short8v v = {};
            if (a < AGENT) {
                const float* src = ahp + ((size_t)b * AGENT + a) * DIM + h * HD + ks * 32 + kgrp * 8;
                float4 r0 = *reinterpret_cast<const float4*>(src);
                float4 r1 = *reinterpret_cast<const float4*>(src + 4);
                v[0] = (short)f2bf(r0.x * SCALE); v[1] = (short)f2bf(r0.y * SCALE);
                v[2] = (short)f2bf(r0.z * SCALE); v[3] = (short)f2bf(r0.w * SCALE);
                v[4] = (short)f2bf(r1.x * SCALE); v[5] = (short)f2bf(r1.y * SCALE);
                v[6] = (short)f2bf(r1.z * SCALE); v[7] = (short)f2bf(r1.w * SCALE);
            }
            qa[ks][mf] = v;
        }

    float mrun[16], lrun[16];
#pragma unroll
    for (int i = 0; i < 16; ++i) { mrun[i] = -1e30f; lrun[i] = 0.f; }
    f32x4 accO[4][4] = {};

    for (int t = wave; t < 13; t += 4) {
        int n0 = t * 64;
        {
            int p = lane & 31, dh = lane >> 5;
            const short* v0p = kvs + (size_t)(b * NPOS + n0 + 2 * p) * (2 * DIM) + DIM + h * HD + dh * 32;
#pragma unroll
            for (int s = 0; s < 4; ++s) {
                short8v va = {}, vb = {};
                if (n0 + 2 * p < NPOS)     va = *reinterpret_cast<const short8v*>(v0p + s * 8);
                if (n0 + 2 * p + 1 < NPOS) vb = *reinterpret_cast<const short8v*>(v0p + 2 * DIM + s * 8);
#pragma unroll
                for (int u = 0; u < 8; ++u) {
                    int d = dh * 32 + s * 8 + u;
                    unsigned int w = ((unsigned int)(unsigned short)va[u]) |
                                     (((unsigned int)(unsigned short)vb[u]) << 16);
                    *reinterpret_cast<unsigned int*>(&VtL[wave][d][2 * p]) = w;
                }
            }
        }

        short8v kb[2][4];
#pragma unroll
        for (int nf = 0; nf < 4; ++nf) {
            int n = n0 + nf * 16 + acol;
            bool val = (n < NPOS);
            const short* kp = kvs + (size_t)(b * NPOS + n) * (2 * DIM) + h * HD + kgrp * 8;
#pragma unroll
            for (int ks = 0; ks < 2; ++ks) {
                short8v v = {};
                if (val) v = *reinterpret_cast<const short8v*>(kp + ks * 32);
                kb[ks][nf] = v;
            }
        }

        f32x4 accS[4][4] = {};
#pragma unroll
        for (int mf = 0; mf < 4; ++mf)
#pragma unroll
            for (int nf = 0; nf < 4; ++nf) {
                accS[mf][nf] = __builtin_amdgcn_mfma_f32_16x16x32_bf16(qa[0][mf], kb[0][nf], accS[mf][nf], 0, 0, 0);
                accS[mf][nf] = __builtin_amdgcn_mfma_f32_16x16x32_bf16(qa[1][mf], kb[1][nf], accS[mf][nf], 0, 0, 0);
            }

#pragma unroll
        for (int mf = 0; mf < 4; ++mf)
#pragma unroll
            for (int r = 0; r < 4; ++r) {
                int a = mf * 16 + kgrp * 4 + r;
                float s[4];
                float mt = -1e30f;
#pragma unroll
                for (int nf = 0; nf < 4; ++nf) {
                    int n = n0 + nf * 16 + acol;
                    float sv = -1e30f;
                    if (n < NPOS) {
                        sv = accS[mf][nf][r];
                        if (a < AGENT) sv += bf2f(pbh[(size_t)a * NPOS + n]);
                    }
                    s[nf] = sv;
                    mt = fmaxf(mt, sv);
                }
#pragma unroll
                for (int off = 1; off < 16; off <<= 1)
                    mt = fmaxf(mt, __shfl_xor(mt, off));
                float mnew = fmaxf(mrun[mf * 4 + r], mt);
                float fac = __expf(mrun[mf * 4 + r] - mnew);
                float ps = 0.f;
#pragma unroll
                for (int nf = 0; nf < 4; ++nf) {
                    float pv = (s[nf] > -1e29f) ? __expf(s[nf] - mnew) : 0.f;
                    ps += pv;
                    pL[wave][a][nf * 16 + acol] = (short)f2bf(pv);
                }
#pragma unroll
                for (int off = 1; off < 16; off <<= 1)
                    ps += __shfl_xor(ps, off);
                mrun[mf * 4 + r] = mnew;
                lrun[mf * 4 + r] = lrun[mf * 4 + r] * fac + ps;
#pragma unroll
                for (int df = 0; df < 4; ++df) accO[mf][df][r] *= fac;
            }

        short8v vb2[2][4];
#pragma unroll
        for (int ks = 0; ks < 2; ++ks)
#pragma unroll
            for (int df = 0; df < 4; ++df)
                vb2[ks][df] = *reinterpret_cast<const short8v*>(
                    &VtL[wave][df * 16 + acol][ks * 32 + kgrp * 8]);
#pragma unroll
        for (int mf = 0; mf < 4; ++mf) {
#pragma unroll
            for (int ks = 0; ks < 2; ++ks) {
                short8v pa = *reinterpret_cast<const short8v*>(
                    &pL[wave][mf * 16 + acol][ks * 32 + kgrp * 8]);
#pragma unroll
                for (int df = 0; df < 4; ++df)
                    accO[mf][df] = __builtin_amdgcn_mfma_f32_16x16x32_bf16(pa, vb2[ks][df], accO[mf][df], 0, 0, 0);
            }
        }
    }

    if (acol == 0) {
#pragma unroll
        for (int mf = 0; mf < 4; ++mf)
#pragma unroll
            for (int r = 0; r < 4; ++r) {
                mw[wave][mf * 16 + kgrp * 4 + r] = mrun[mf * 4 + r];
                lw[wave][mf * 16 + kgrp * 4 + r] = lrun[mf * 4 + r];
            }
    }
    __syncthreads();
#pragma unroll
    for (int mf = 0; mf < 4; ++mf)
#pragma unroll
        for (int df = 0; df < 4; ++df)
#pragma unroll
            for (int r = 0; r < 4; ++r)
                Om[wave][mf * 16 + kgrp * 4 + r][df * 16 + acol] = accO[mf][df][r];
    __syncthreads();

    for (int idx = tid; idx < AGENT * HD; idx += 256) {
        int a = idx >> 6, d = idx & 63;
        float m = fmaxf(fmaxf(mw[0][a], mw[1][a]), fmaxf(mw[2][a], mw[3][a]));
        float l = 0.f, o = 0.f;
#pragma unroll
        for (int w = 0; w < 4; ++w) {
            float f = __expf(mw[w][a] - m);
            l += f * lw[w][a];
            o += f * Om[w][a][d];
        }
        ((short*)agent_v)[(((size_t)b * HEADS + h) * AGENT + a) * HD + d] = (short)f2bf(o / l);
    }
}

// ---------------------------------------------------------------------------
// Q attention via MFMA (conv split out), in-place over q.
// ---------------------------------------------------------------------------
__global__ __launch_bounds__(256, 4) void q_attn_mfma(
    bf16* qpre0, const float* __restrict__ ahp_x0, const bf16* __restrict__ ab_x0,
    const bf16* __restrict__ agv_x0,
    bf16* qpre1, const float* __restrict__ ahp_x1, const bf16* __restrict__ ab_x1,
    const bf16* __restrict__ agv_x1)
{
    __shared__ short pL[4][16][72];
    __shared__ float oL[4][16][68];

    int sel = blockIdx.x >= BATCH * HEADS * 2;
    int blk = blockIdx.x - sel * BATCH * HEADS * 2;
    bf16* qpre = sel ? qpre1 : qpre0;
    const float* ahp_x = sel ? ahp_x1 : ahp_x0;
    const bf16* ab_x = sel ? ab_x1 : ab_x0;
    const bf16* agv_x = sel ? agv_x1 : agv_x0;

    int half = blk & 1;
    int h = (blk >> 1) % HEADS;
    int b = blk / (2 * HEADS);
    int tid = threadIdx.x;
    int wave = tid >> 6, lane = tid & 63;
    int acol = lane & 15, kgrp = lane >> 4;

    for (int i = tid; i < 4 * 16 * 72; i += 256)
        ((short*)pL)[i] = 0;

    short8v bs[2][4];
#pragma unroll
    for (int ks = 0; ks < 2; ++ks)
#pragma unroll
        for (int nf = 0; nf < 4; ++nf) {
            int a = nf * 16 + acol;
            short8v v = {};
            if (a < AGENT) {
                const float* src = ahp_x + ((size_t)b * AGENT + a) * DIM + h * HD + ks * 32 + kgrp * 8;
                float4 r0 = *reinterpret_cast<const float4*>(src);
                float4 r1 = *reinterpret_cast<const float4*>(src + 4);
                v[0] = (short)f2bf(r0.x * SCALE); v[1] = (short)f2bf(r0.y * SCALE);
                v[2] = (short)f2bf(r0.z * SCALE); v[3] = (short)f2bf(r0.w * SCALE);
                v[4] = (short)f2bf(r1.x * SCALE); v[5] = (short)f2bf(r1.y * SCALE);
                v[6] = (short)f2bf(r1.z * SCALE); v[7] = (short)f2bf(r1.w * SCALE);
            }
            bs[ks][nf] = v;
        }

    const short* agvs = (const short*)agv_x;
    short8v bv[2][4];
#pragma unroll
    for (int ks = 0; ks < 2; ++ks)
#pragma unroll
        for (int nf = 0; nf < 4; ++nf) {
            int d = nf * 16 + acol;
            short8v v = {};
#pragma unroll
            for (int i = 0; i < 8; ++i) {
                int a = ks * 32 + kgrp * 8 + i;
                if (a < AGENT)
                    v[i] = agvs[(((size_t)b * HEADS + h) * AGENT + a) * HD + d];
            }
            bv[ks][nf] = v;
        }

    __syncthreads();

    int tstart = half ? 25 : 0, tend = half ? 49 : 25;
    for (int t = tstart + wave; t < tend; t += 4) {
        int n0 = t * 16;
        const short* qrow = (const short*)qpre +
            ((size_t)(b * NPOS + n0 + acol)) * DIM + h * HD + kgrp * 8;
        short8v a0 = *reinterpret_cast<const short8v*>(qrow);
        short8v a1 = *reinterpret_cast<const short8v*>(qrow + 32);

        f32x4 accs[4] = {};
#pragma unroll
        for (int nf = 0; nf < 4; ++nf) {
            accs[nf] = __builtin_amdgcn_mfma_f32_16x16x32_bf16(a0, bs[0][nf], accs[nf], 0, 0, 0);
            accs[nf] = __builtin_amdgcn_mfma_f32_16x16x32_bf16(a1, bs[1][nf], accs[nf], 0, 0, 0);
        }

        float inv[4];
#pragma unroll
        for (int r = 0; r < 4; ++r) {
            int n = n0 + kgrp * 4 + r;
            float sarr[4];
            float m = -1e30f;
#pragma unroll
            for (int nf = 0; nf < 4; ++nf) {
                int a = nf * 16 + acol;
                float s = -1e30f;
                if (a < AGENT)
                    s = accs[nf][r] + bf2f(ab_x[((size_t)h * NPOS + n) * AGENT + a]);
                sarr[nf] = s;
                m = fmaxf(m, s);
            }
#pragma unroll
            for (int off = 1; off < 16; off <<= 1)
                m = fmaxf(m, __shfl_xor(m, off));
            float ls = 0.f;
#pragma unroll
            for (int nf = 0; nf < 4; ++nf) {
                float p = (sarr[nf] > -1e29f) ? __expf(sarr[nf] - m) : 0.f;
                sarr[nf] = p;
                ls += p;
            }
#pragma unroll
            for (int off = 1; off < 16; off <<= 1)
                ls += __shfl_xor(ls, off);
            inv[r] = 1.f / ls;
#pragma unroll
            for (int nf = 0; nf < 4; ++nf) {
                int a = nf * 16 + acol;
                if (a < AGENT)
                    pL[wave][kgrp * 4 + r][a] = (short)f2bf(sarr[nf]);
            }
        }

        short8v p0 = *reinterpret_cast<const short8v*>(&pL[wave][acol][kgrp * 8]);
        short8v p1 = *reinterpret_cast<const short8v*>(&pL[wave][acol][kgrp * 8 + 32]);

        f32x4 acco[4] = {};
#pragma unroll
        for (int nf = 0; nf < 4; ++nf) {
            acco[nf] = __builtin_amdgcn_mfma_f32_16x16x32_bf16(p0, bv[0][nf], acco[nf], 0, 0, 0);
            acco[nf] = __builtin_amdgcn_mfma_f32_16x16x32_bf16(p1, bv[1][nf], acco[nf], 0, 0, 0);
        }

#pragma unroll
        for (int r = 0; r < 4; ++r)
#pragma unroll
            for (int nf = 0; nf < 4; ++nf)
                oL[wave][kgrp * 4 + r][nf * 16 + acol] = acco[nf][r] * inv[r];

#pragma unroll
        for (int it2 = 0; it2 < 2; ++it2) {
            int item = lane + 64 * it2;
            int rl = item >> 3, d8 = item & 7;
            int n = n0 + rl;
            float4 o0 = *reinterpret_cast<const float4*>(&oL[wave][rl][d8 * 8]);
            float4 o1 = *reinterpret_cast<const float4*>(&oL[wave][rl][d8 * 8 + 4]);
            short8v ov;
            ov[0] = (short)f2bf(o0.x); ov[1] = (short)f2bf(o0.y);
            ov[2] = (short)f2bf(o0.z); ov[3] = (short)f2bf(o0.w);
            ov[4] = (short)f2bf(o1.x); ov[5] = (short)f2bf(o1.y);
            ov[6] = (short)f2bf(o1.z); ov[7] = (short)f2bf(o1.w);
            *reinterpret_cast<short8v*>((short*)qpre +
                ((size_t)(b * NPOS + n)) * DIM + h * HD + d8 * 8) = ov;
        }
    }
}

// ---------------------------------------------------------------------------
// Depthwise 3x3 conv, LDS-tiled: pre += conv(V) + bias. Both modalities.
// ---------------------------------------------------------------------------
__global__ __launch_bounds__(256, 3) void dwc_kernel(
    bf16* pre0, const bf16* __restrict__ kv0,
    const float* __restrict__ w0, const float* __restrict__ b0,
    bf16* pre1, const bf16* __restrict__ kv1,
    const float* __restrict__ w1, const float* __restrict__ b1)
{
    __shared__ __align__(16) short Vs[168][136];
    __shared__ float wS[9][128];
    __shared__ float cbS[128];

    int blk = blockIdx.x;
    int per = BATCH * CONV_CG * CONV_IG;
    int sel = blk >= per;
    blk -= sel * per;
    bf16* pre = sel ? pre1 : pre0;
    const short* kvs = (const short*)(sel ? kv1 : kv0);
    const float* dw = sel ? w1 : w0;
    const float* db = sel ? b1 : b0;

    int ig = blk % CONV_IG;
    int cg = (blk / CONV_IG) % CONV_CG;
    int b  = blk / (CONV_IG * CONV_CG);
    int c0 = cg * 128;
    int tid = threadIdx.x;

    for (int i = tid; i < 9 * 128; i += 256)
        wS[i >> 7][i & 127] = dw[(i >> 7) * DIM + c0 + (i & 127)];
    if (tid < 128) cbS[tid] = db[c0 + tid];

    for (int it = 0; it < 11; ++it) {
        int item = tid + 256 * it;
        if (item >= 168 * 16) break;
        int pos = item >> 4, c8 = item & 15;
        int ii = pos / 28, jj = pos % 28;
        int irow = ig * 4 - 1 + ii;
        short8v v = {};
        if (irow >= 0 && irow < HH)
            v = *reinterpret_cast<const short8v*>(
                kvs + (size_t)(b * NPOS + irow * WW + jj) * (2 * DIM) + DIM + c0 + c8 * 8);
        *reinterpret_cast<short8v*>(&Vs[pos][c8 * 8]) = v;
    }
    __syncthreads();

#pragma unroll
    for (int it = 0; it < 7; ++it) {
        int item = tid + 256 * it;
        int opos = item >> 4, c8 = item & 15;
        int oi = opos / 28, oj = opos % 28;
        int n = (ig * 4 + oi) * WW + oj;
        short* pp = (short*)pre + (size_t)(b * NPOS + n) * DIM + c0 + c8 * 8;
        short8v pv = *reinterpret_cast<const short8v*>(pp);
        float acc[8];
#pragma unroll
        for (int u = 0; u < 8; ++u) acc[u] = bfs2f(pv[u]) + cbS[c8 * 8 + u];
#pragma unroll
        for (int di = -1; di <= 1; ++di) {
#pragma unroll
            for (int dj = -1; dj <= 1; ++dj) {
                int jj = oj + dj;
                if (jj < 0 || jj >= WW) continue;
                int pos = (oi + 1 + di) * 28 + jj;
                short8v vv = *reinterpret_cast<const short8v*>(&Vs[pos][c8 * 8]);
                int tap = (di + 1) * 3 + (dj + 1);
#pragma unroll
                for (int u = 0; u < 8; ++u)
                    acc[u] += wS[tap][c8 * 8 + u] * bfs2f(vv[u]);
            }
        }
        short8v ov;
#pragma unroll
        for (int u = 0; u < 8; ++u) ov[u] = (short)f2bf(acc[u]);
        *reinterpret_cast<short8v*>(pp) = ov;
    }
}

// ---------------------------------------------------------------------------
extern "C" void kernel_launch(void* const* d_in, const int* in_sizes, int n_in,
                              void* d_out, int out_size, void* d_ws, size_t ws_size,
                              hipStream_t stream)
{
    const float* rgb_fea    = (const float*)d_in[0];
    const float* depth_fea  = (const float*)d_in[1];
    const float* rgb_q_w    = (const float*)d_in[2];
    const float* rgb_kv_w   = (const float*)d_in[3];
    const float* rgb_proj_w = (const float*)d_in[4];
    const float* rgb_proj_b = (const float*)d_in[5];
    const float* depth_q_w    = (const float*)d_in[6];
    const float* depth_kv_w   = (const float*)d_in[7];
    const float* depth_proj_w = (const float*)d_in[8];
    const float* depth_proj_b = (const float*)d_in[9];
    const float* rgb_dwc_w   = (const float*)d_in[10];
    const float* rgb_dwc_b   = (const float*)d_in[11];
    const float* depth_dwc_w = (const float*)d_in[12];
    const float* depth_dwc_b = (const float*)d_in[13];
    const float* rgb_an   = (const float*)d_in[14];
    const float* rgb_na   = (const float*)d_in[15];
    const float* rgb_ah_b = (const float*)d_in[16];
    const float* rgb_aw_b = (const float*)d_in[17];
    const float* rgb_ha_b = (const float*)d_in[18];
    const float* rgb_wa_b = (const float*)d_in[19];
    const float* depth_an   = (const float*)d_in[20];
    const float* depth_na   = (const float*)d_in[21];
    const float* depth_ah_b = (const float*)d_in[22];
    const float* depth_aw_b = (const float*)d_in[23];
    const float* depth_ha_b = (const float*)d_in[24];
    const float* depth_wa_b = (const float*)d_in[25];

    char* ws = (char*)d_ws;
    size_t off = 0;
    auto alloc = [&](size_t bytes) -> void* {
        void* p = ws + off;
        off += (bytes + 255) & ~(size_t)255;
        return p;
    };
    bf16* rgb_q    = (bf16*)alloc((size_t)MROWS * DIM * 2);
    bf16* depth_q  = (bf16*)alloc((size_t)MROWS * DIM * 2);
    bf16* rgb_kv   = (bf16*)alloc((size_t)MROWS * 2 * DIM * 2);
    bf16* depth_kv = (bf16*)alloc((size_t)MROWS * 2 * DIM * 2);
    bf16* rgb_pb    = (bf16*)alloc((size_t)HEADS * AGENT * NPOS * 2);
    bf16* depth_pb  = (bf16*)alloc((size_t)HEADS * AGENT * NPOS * 2);
    bf16* rgb_ab    = (bf16*)alloc((size_t)HEADS * NPOS * AGENT * 2);
    bf16* depth_ab  = (bf16*)alloc((size_t)HEADS * NPOS * AGENT * 2);
    bf16* rgb_agv   = (bf16*)alloc((size_t)BATCH * HEADS * AGENT * HD * 2);
    bf16* depth_agv = (bf16*)alloc((size_t)BATCH * HEADS * AGENT * HD * 2);
    bf16* proj_wt_r = (bf16*)alloc((size_t)DIM * DIM * 2);
    bf16* proj_wt_d = (bf16*)alloc((size_t)DIM * DIM * 2);
    size_t ubase = off;
    // combined [q|kv]^T weights: [2304][768] bf16 each modality
    bf16* comb_wt_r = (bf16*)alloc((size_t)3 * DIM * DIM * 2);
    bf16* comb_wt_d = (bf16*)alloc((size_t)3 * DIM * DIM * 2);
    off = ubase;  // alias (weights dead before ahp written)
    float* rgb_ahp   = (float*)alloc((size_t)BATCH * AGENT * DIM * 4);
    float* depth_ahp = (float*)alloc((size_t)BATCH * AGENT * DIM * 4);

    // d_out doubles as scratch for the bf16-converted activations
    bf16* fea_bf_r = (bf16*)d_out;
    bf16* fea_bf_d = fea_bf_r + (size_t)MROWS * DIM;

    dim3 blk(256);
    int n8 = MROWS * DIM / 8;

    // 0) activation f32->bf16 + weight transposes into combined buffers
    convert_bf16_2<<<(2 * n8 + 255) / 256, blk, 0, stream>>>(rgb_fea, fea_bf_r, depth_fea, fea_bf_d, n8);
    transpose_w_bf16_2<<<dim3(24, 48), blk, 0, stream>>>(rgb_q_w, comb_wt_r, depth_q_w, comb_wt_d, DIM, DIM);
    transpose_w_bf16_2<<<dim3(48, 48), blk, 0, stream>>>(rgb_kv_w, comb_wt_r + (size_t)DIM * DIM,
                                                          depth_kv_w, comb_wt_d + (size_t)DIM * DIM, DIM, 2 * DIM);
    transpose_w_bf16_2<<<dim3(24, 48), blk, 0, stream>>>(rgb_proj_w, proj_wt_r, depth_proj_w, proj_wt_d, DIM, DIM);

    // 1) q+kv projections fused: one N=2304 GEMM per modality pair,
    //    column-split routing (cols<768 -> q, >=768 -> kv)
    gemm_mfma<false><<<dim3(18, 392), blk, 0, stream>>>(
        fea_bf_r, comb_wt_r, nullptr, rgb_q, rgb_kv,
        fea_bf_d, comb_wt_d, nullptr, depth_q, depth_kv,
        MROWS, 3 * DIM, DIM, DIM);

    // 2) agent pooling (merged)
    pool_kernel_2<<<(2 * BATCH * AGENT * DIM + 255) / 256, blk, 0, stream>>>(
        rgb_q, rgb_ahp, depth_q, depth_ahp);

    // 3) position biases (merged pairs)
    pos_bias_kernel_2<<<(2 * HEADS * AGENT * NPOS + 255) / 256, blk, 0, stream>>>(
        rgb_an, rgb_ah_b, rgb_aw_b, rgb_pb,
        depth_an, depth_ah_b, depth_aw_b, depth_pb);
    ag_bias_kernel_2<<<(2 * HEADS * NPOS * AGENT + 255) / 256, blk, 0, stream>>>(
        rgb_na, rgb_ha_b, rgb_wa_b, rgb_ab,
        depth_na, depth_ha_b, depth_wa_b, depth_ab);

    // 4) cross-modal agent aggregation (both modalities, one dispatch)
    agent_attn3<<<2 * BATCH * HEADS, blk, 0, stream>>>(
        depth_ahp, rgb_kv, rgb_pb, depth_agv,
        rgb_ahp, depth_kv, depth_pb, rgb_agv);

    // 5) agent broadcast (in-place q -> attention output)
    q_attn_mfma<<<2 * BATCH * HEADS * 2, blk, 0, stream>>>(
        rgb_q, depth_ahp, depth_ab, depth_agv,
        depth_q, rgb_ahp, rgb_ab, rgb_agv);

    // 5b) depthwise conv added in (LDS-tiled, both modalities)
    dwc_kernel<<<2 * BATCH * CONV_CG * CONV_IG, blk, 0, stream>>>(
        rgb_q, rgb_kv, rgb_dwc_w, rgb_dwc_b,
        depth_q, depth_kv, depth_dwc_w, depth_dwc_b);

    // 6) output projections (merged; overwrite d_out scratch with results)
    float* out = (float*)d_out;
    gemm_mfma<true><<<dim3(6, 392), blk, 0, stream>>>(
        rgb_q, proj_wt_r, rgb_proj_b, out, nullptr,
        depth_q, proj_wt_d, depth_proj_b, out + (size_t)MROWS * DIM, nullptr,
        MROWS, DIM, DIM, 0);
}

// Round 16
// 633.763 us; speedup vs baseline: 1.1908x; 1.0043x over previous
//
#include <hip/hip_runtime.h>
#include <hip/hip_bf16.h>

#define BATCH 32
#define NPOS 784
#define DIM 768
#define HEADS 12
#define HD 64
#define AGENT 49
#define HH 28
#define WW 28
#define MROWS (BATCH*NPOS)   // 25088
#define SCALE 0.125f
#define CONV_CG 6
#define CONV_IG 7

// prologue megakernel block ranges
#define N8C   (MROWS*DIM/8)          // 2408448
#define NB_CONV ((2*N8C)/256)        // 18816 (exact)
#define NB_TQ  (24*48)               // 1152
#define NB_TKV (48*48)               // 2304
#define NB_TP  (24*48)               // 1152
#define NB_PB  ((2*HEADS*AGENT*NPOS + 255)/256)  // 3602
#define NB_AB  ((2*HEADS*NPOS*AGENT + 255)/256)  // 3602
#define NB_PROLOGUE (NB_CONV+NB_TQ+NB_TKV+NB_TP+NB_PB+NB_AB)

using bf16 = __hip_bfloat16;
typedef __attribute__((ext_vector_type(4))) float f32x4;
typedef __attribute__((ext_vector_type(8))) short short8v;

__device__ __forceinline__ float bf2f(bf16 x) { return __bfloat162float(x); }
__device__ __forceinline__ float bfs2f(short s) {
    unsigned int u = ((unsigned int)(unsigned short)s) << 16;
    return __uint_as_float(u);
}
__device__ __forceinline__ unsigned short f2bf(float x) {
    unsigned int u = __float_as_uint(x);
    unsigned int r = (u + 0x7fffu + ((u >> 16) & 1u)) >> 16;
    return (unsigned short)r;
}

#define GLOAD_LDS16(g, l) __builtin_amdgcn_global_load_lds( \
    (const __attribute__((address_space(1))) unsigned int*)(g), \
    (__attribute__((address_space(3))) unsigned int*)(l), 16, 0, 0)

// ---------------------------------------------------------------------------
// Bilinear 7->28 upsample, half-pixel centers, edge clamp
// ---------------------------------------------------------------------------
__device__ __forceinline__ float bilerp7(const float* __restrict__ img, int i, int j)
{
    float si = 0.25f * i - 0.375f, sj = 0.25f * j - 0.375f;
    int i0 = (int)floorf(si); float fi = si - i0;
    int j0 = (int)floorf(sj); float fj = sj - j0;
    int i0c = min(max(i0, 0), 6), i1c = min(max(i0 + 1, 0), 6);
    int j0c = min(max(j0, 0), 6), j1c = min(max(j0 + 1, 0), 6);
    float v00 = img[i0c * 7 + j0c], v01 = img[i0c * 7 + j1c];
    float v10 = img[i1c * 7 + j0c], v11 = img[i1c * 7 + j1c];
    return (1.f - fi) * ((1.f - fj) * v00 + fj * v01) + fi * ((1.f - fj) * v10 + fj * v11);
}

// ---------------------------------------------------------------------------
// Prologue megakernel: convert(2) | transpose q pair | transpose kv pair |
// transpose proj pair | pos_bias pair | ag_bias pair — block-range dispatch.
// All sub-bodies independent; aggregate is HBM-BW-bound (~485 MB).
// ---------------------------------------------------------------------------
__global__ __launch_bounds__(256) void prologue_kernel(
    const float* __restrict__ rgb_fea, bf16* __restrict__ fea_bf_r,
    const float* __restrict__ depth_fea, bf16* __restrict__ fea_bf_d,
    const float* __restrict__ rgb_q_w, const float* __restrict__ depth_q_w,
    const float* __restrict__ rgb_kv_w, const float* __restrict__ depth_kv_w,
    const float* __restrict__ rgb_proj_w, const float* __restrict__ depth_proj_w,
    bf16* __restrict__ comb_wt_r, bf16* __restrict__ comb_wt_d,
    bf16* __restrict__ proj_wt_r, bf16* __restrict__ proj_wt_d,
    const float* __restrict__ rgb_an, const float* __restrict__ rgb_ah_b,
    const float* __restrict__ rgb_aw_b, bf16* __restrict__ rgb_pb,
    const float* __restrict__ depth_an, const float* __restrict__ depth_ah_b,
    const float* __restrict__ depth_aw_b, bf16* __restrict__ depth_pb,
    const float* __restrict__ rgb_na, const float* __restrict__ rgb_ha_b,
    const float* __restrict__ rgb_wa_b, bf16* __restrict__ rgb_ab,
    const float* __restrict__ depth_na, const float* __restrict__ depth_ha_b,
    const float* __restrict__ depth_wa_b, bf16* __restrict__ depth_ab)
{
    __shared__ float t[32][33];
    int blk = blockIdx.x;
    int tid = threadIdx.x;

    if (blk < NB_CONV) {
        // -------- activation f32 -> bf16 (both tensors)
        int idx = blk * 256 + tid;
        int sel = idx >= N8C;
        int li = idx - sel * N8C;
        const float* p = (sel ? depth_fea : rgb_fea) + (size_t)li * 8;
        float4 r0 = *reinterpret_cast<const float4*>(p);
        float4 r1 = *reinterpret_cast<const float4*>(p + 4);
        short8v v;
        v[0] = (short)f2bf(r0.x); v[1] = (short)f2bf(r0.y);
        v[2] = (short)f2bf(r0.z); v[3] = (short)f2bf(r0.w);
        v[4] = (short)f2bf(r1.x); v[5] = (short)f2bf(r1.y);
        v[6] = (short)f2bf(r1.z); v[7] = (short)f2bf(r1.w);
        *reinterpret_cast<short8v*>((short*)(sel ? fea_bf_d : fea_bf_r) + (size_t)li * 8) = v;
        return;
    }
    blk -= NB_CONV;

    if (blk < NB_TQ + NB_TKV + NB_TP) {
        // -------- weight transpose+convert pairs
        const float *W0, *W1; bf16 *Wt0, *Wt1; int K, N, gx, lb;
        if (blk < NB_TQ) {
            lb = blk; gx = 24; K = DIM; N = DIM;
            W0 = rgb_q_w; Wt0 = comb_wt_r;
            W1 = depth_q_w; Wt1 = comb_wt_d;
        } else if (blk < NB_TQ + NB_TKV) {
            lb = blk - NB_TQ; gx = 48; K = DIM; N = 2 * DIM;
            W0 = rgb_kv_w; Wt0 = comb_wt_r + (size_t)DIM * DIM;
            W1 = depth_kv_w; Wt1 = comb_wt_d + (size_t)DIM * DIM;
        } else {
            lb = blk - NB_TQ - NB_TKV; gx = 24; K = DIM; N = DIM;
            W0 = rgb_proj_w; Wt0 = proj_wt_r;
            W1 = depth_proj_w; Wt1 = proj_wt_d;
        }
        int bx = lb % gx, by = lb / gx;
        int gyh = 24;
        int sel = by >= gyh;
        const float* W = sel ? W1 : W0;
        bf16* Wt = sel ? Wt1 : Wt0;
        int tx = tid & 31, ty = tid >> 5;
        int k0 = (by - sel * gyh) * 32, n0 = bx * 32;
#pragma unroll
        for (int i = 0; i < 4; ++i)
            t[ty + 8 * i][tx] = W[(size_t)(k0 + ty + 8 * i) * N + n0 + tx];
        __syncthreads();
#pragma unroll
        for (int i = 0; i < 4; ++i)
            Wt[(size_t)(n0 + ty + 8 * i) * K + k0 + tx] = __float2bfloat16(t[tx][ty + 8 * i]);
        return;
    }
    blk -= NB_TQ + NB_TKV + NB_TP;

    if (blk < NB_PB) {
        // -------- pos_bias pair: pb[h][a][n]
        int idx = blk * 256 + tid;
        int tot = HEADS * AGENT * NPOS;
        if (idx >= 2 * tot) return;
        int sel = idx >= tot;
        int li = idx - sel * tot;
        const float* an = sel ? depth_an : rgb_an;
        const float* ah_b = sel ? depth_ah_b : rgb_ah_b;
        const float* aw_b = sel ? depth_aw_b : rgb_aw_b;
        bf16* pb = sel ? depth_pb : rgb_pb;
        int n = li % NPOS;
        int a = (li / NPOS) % AGENT;
        int h = li / (NPOS * AGENT);
        int i = n / WW, j = n % WW;
        float v = bilerp7(an + (size_t)(h * AGENT + a) * 49, i, j);
        v += ah_b[(h * AGENT + a) * HH + i] + aw_b[(h * AGENT + a) * WW + j];
        pb[li] = __float2bfloat16(v);
        return;
    }
    blk -= NB_PB;

    {
        // -------- ag_bias pair: ab[h][n][a]
        int idx = blk * 256 + tid;
        int tot = HEADS * NPOS * AGENT;
        if (idx >= 2 * tot) return;
        int sel = idx >= tot;
        int li = idx - sel * tot;
        const float* na = sel ? depth_na : rgb_na;
        const float* ha_b = sel ? depth_ha_b : rgb_ha_b;
        const float* wa_b = sel ? depth_wa_b : rgb_wa_b;
        bf16* ab = sel ? depth_ab : rgb_ab;
        int a = li % AGENT;
        int n = (li / AGENT) % NPOS;
        int h = li / (AGENT * NPOS);
        int i = n / WW, j = n % WW;
        float v = bilerp7(na + (size_t)(h * AGENT + a) * 49, i, j);
        v += ha_b[(h * HH + i) * AGENT + a] + wa_b[(h * WW + j) * AGENT + a];
        ab[li] = __float2bfloat16(v);
    }
}

// ---------------------------------------------------------------------------
// MFMA GEMM (merged rgb+depth; optional N-split routing to two C buffers)
// ---------------------------------------------------------------------------
template<bool OUTF32>
__global__ __launch_bounds__(256, 4) void gemm_mfma(
    const bf16* __restrict__ A0, const bf16* __restrict__ Bt0,
    const float* __restrict__ bias0, void* __restrict__ CpA0, void* __restrict__ CpB0,
    const bf16* __restrict__ A1, const bf16* __restrict__ Bt1,
    const float* __restrict__ bias1, void* __restrict__ CpA1, void* __restrict__ CpB1,
    int M, int N, int K, int nsplit)
{
    __shared__ __align__(16) short As[128 * 64];
    __shared__ __align__(16) short Bs[128 * 64];

    int tid = threadIdx.x;
    int wave = tid >> 6, lane = tid & 63;

    int gx = gridDim.x;
    int gyh = gridDim.y >> 1;
    int nwg = gx * gridDim.y;
    int bid = blockIdx.y * gx + blockIdx.x;
    int cpx = nwg >> 3;
    int nb = (bid & 7) * cpx + (bid >> 3);
    int rowblk = nb / gx;
    int prob = rowblk >= gyh;
    int m0 = (rowblk - prob * gyh) * 128, n0 = (nb % gx) * 128;

    const short* Ab  = (const short*)(prob ? A1 : A0);
    const short* Btb = (const short*)(prob ? Bt1 : Bt0);
    const float* bias = prob ? bias1 : bias0;

    void* Cp; int Ns; int cb;
    if (nsplit > 0 && n0 >= nsplit) {
        Cp = prob ? CpB1 : CpB0; Ns = N - nsplit; cb = n0 - nsplit;
    } else {
        Cp = prob ? CpA1 : CpA0; Ns = (nsplit > 0) ? nsplit : N; cb = n0;
    }

    int wm = (wave >> 1) * 64, wn = (wave & 1) * 64;
    int acol = lane & 15, kgrp = lane >> 4;

    f32x4 acc[4][4] = {};

    for (int k0 = 0; k0 < K; k0 += 64) {
#pragma unroll
        for (int it = 0; it < 4; ++it) {
            int idx = tid + 256 * it;
            int row = idx >> 3, seg = idx & 7;
            int sseg = seg ^ (row & 7);
            GLOAD_LDS16(Ab + (size_t)(m0 + row) * K + k0 + sseg * 8, &As[idx * 8]);
        }
#pragma unroll
        for (int it = 0; it < 4; ++it) {
            int idx = tid + 256 * it;
            int row = idx >> 3, seg = idx & 7;
            int sseg = seg ^ (row & 7);
            GLOAD_LDS16(Btb + (size_t)(n0 + row) * K + k0 + sseg * 8, &Bs[idx * 8]);
        }
        __syncthreads();

#pragma unroll
        for (int kk = 0; kk < 2; ++kk) {
            short8v af[4], bfr[4];
#pragma unroll
            for (int mf = 0; mf < 4; ++mf) {
                int row = wm + mf * 16 + acol;
                int seg = (kk * 4 + kgrp) ^ (row & 7);
                af[mf] = *reinterpret_cast<const short8v*>(&As[row * 64 + seg * 8]);
            }
#pragma unroll
            for (int nf = 0; nf < 4; ++nf) {
                int row = wn + nf * 16 + acol;
                int seg = (kk * 4 + kgrp) ^ (row & 7);
                bfr[nf] = *reinterpret_cast<const short8v*>(&Bs[row * 64 + seg * 8]);
            }
#pragma unroll
            for (int mf = 0; mf < 4; ++mf)
#pragma unroll
                for (int nf = 0; nf < 4; ++nf)
                    acc[mf][nf] = __builtin_amdgcn_mfma_f32_16x16x32_bf16(
                        af[mf], bfr[nf], acc[mf][nf], 0, 0, 0);
        }
        __syncthreads();
    }

    int rgrp = kgrp * 4, cidx = acol;
#pragma unroll
    for (int mf = 0; mf < 4; ++mf)
#pragma unroll
        for (int nf = 0; nf < 4; ++nf)
#pragma unroll
            for (int r = 0; r < 4; ++r) {
                int row = m0 + wm + mf * 16 + rgrp + r;
                int col = cb + wn + nf * 16 + cidx;
                float v = acc[mf][nf][r];
                if constexpr (OUTF32)
                    ((float*)Cp)[(size_t)row * Ns + col] = v + bias[col];
                else
                    ((bf16*)Cp)[(size_t)row * Ns + col] = __float2bfloat16(v);
            }
}

// ---------------------------------------------------------------------------
// Pool pair
// ---------------------------------------------------------------------------
__global__ void pool_kernel_2(const bf16* __restrict__ q0, float* __restrict__ ahp0,
                              const bf16* __restrict__ q1, float* __restrict__ ahp1)
{
    int idx = blockIdx.x * 256 + threadIdx.x;
    int tot = BATCH * AGENT * DIM;
    if (idx >= 2 * tot) return;
    int sel = idx >= tot;
    int li = idx - sel * tot;
    const bf16* q = sel ? q1 : q0;
    float* ahp = sel ? ahp1 : ahp0;
    int c = li % DIM;
    int a = (li / DIM) % AGENT;
    int b = li / (DIM * AGENT);
    int ai = a / 7, aj = a % 7;
    float s = 0.f;
#pragma unroll
    for (int u = 0; u < 4; ++u)
#pragma unroll
        for (int v = 0; v < 4; ++v) {
            int n = (ai * 4 + u) * WW + (aj * 4 + v);
            s += bf2f(q[((size_t)b * NPOS + n) * DIM + c]);
        }
    ahp[li] = s * (1.f / 16.f);
}

// ---------------------------------------------------------------------------
// Agent attention v3 (full MFMA), both modalities in one dispatch.
// ---------------------------------------------------------------------------
__global__ __launch_bounds__(256, 2) void agent_attn3(
    const float* __restrict__ ahp0, const bf16* __restrict__ kv0,
    const bf16* __restrict__ pb0, bf16* __restrict__ agent_v0,
    const float* __restrict__ ahp1, const bf16* __restrict__ kv1,
    const bf16* __restrict__ pb1, bf16* __restrict__ agent_v1)
{
    __shared__ __align__(16) char smem[75776];
    short (*pL)[64][72]  = (short (*)[64][72])smem;
    short (*VtL)[64][72] = (short (*)[64][72])(smem + 36864);
    float (*Om)[64][66]  = (float (*)[64][66])smem;
    float (*mw)[64]      = (float (*)[64])(smem + 73728);
    float (*lw)[64]      = (float (*)[64])(smem + 74752);

    int sel = blockIdx.x >= BATCH * HEADS;
    int blk = blockIdx.x - sel * BATCH * HEADS;
    const float* ahp = sel ? ahp1 : ahp0;
    const bf16* kv = sel ? kv1 : kv0;
    const bf16* pb = sel ? pb1 : pb0;
    bf16* agent_v = sel ? agent_v1 : agent_v0;

    int tid = threadIdx.x;
    int wave = tid >> 6, lane = tid & 63;
    int acol = lane & 15, kgrp = lane >> 4;
    int h = blk % HEADS;
    int b = blk / HEADS;
    const short* kvs = (const short*)kv;
    const bf16* pbh = pb + (size_t)h * AGENT * NPOS;

    short8v qa[2][4];
#pragma unroll
    for (int ks = 0; ks < 2; ++ks)
#pragma unroll
        for (int mf = 0; mf < 4; ++mf) {
            int a = mf * 16 + acol;
            short8v v = {};
            if (a < AGENT) {
                const float* src = ahp + ((size_t)b * AGENT + a) * DIM + h * HD + ks * 32 + kgrp * 8;
                float4 r0 = *reinterpret_cast<const float4*>(src);
                float4 r1 = *reinterpret_cast<const float4*>(src + 4);
                v[0] = (short)f2bf(r0.x * SCALE); v[1] = (short)f2bf(r0.y * SCALE);
                v[2] = (short)f2bf(r0.z * SCALE); v[3] = (short)f2bf(r0.w * SCALE);
                v[4] = (short)f2bf(r1.x * SCALE); v[5] = (short)f2bf(r1.y * SCALE);
                v[6] = (short)f2bf(r1.z * SCALE); v[7] = (short)f2bf(r1.w * SCALE);
            }
            qa[ks][mf] = v;
        }

    float mrun[16], lrun[16];
#pragma unroll
    for (int i = 0; i < 16; ++i) { mrun[i] = -1e30f; lrun[i] = 0.f; }
    f32x4 accO[4][4] = {};

    for (int t = wave; t < 13; t += 4) {
        int n0 = t * 64;
        {
            int p = lane & 31, dh = lane >> 5;
            const short* v0p = kvs + (size_t)(b * NPOS + n0 + 2 * p) * (2 * DIM) + DIM + h * HD + dh * 32;
#pragma unroll
            for (int s = 0; s < 4; ++s) {
                short8v va = {}, vb = {};
                if (n0 + 2 * p < NPOS)     va = *reinterpret_cast<const short8v*>(v0p + s * 8);
                if (n0 + 2 * p + 1 < NPOS) vb = *reinterpret_cast<const short8v*>(v0p + 2 * DIM + s * 8);
#pragma unroll
                for (int u = 0; u < 8; ++u) {
                    int d = dh * 32 + s * 8 + u;
                    unsigned int w = ((unsigned int)(unsigned short)va[u]) |
                                     (((unsigned int)(unsigned short)vb[u]) << 16);
                    *reinterpret_cast<unsigned int*>(&VtL[wave][d][2 * p]) = w;
                }
            }
        }

        short8v kb[2][4];
#pragma unroll
        for (int nf = 0; nf < 4; ++nf) {
            int n = n0 + nf * 16 + acol;
            bool val = (n < NPOS);
            const short* kp = kvs + (size_t)(b * NPOS + n) * (2 * DIM) + h * HD + kgrp * 8;
#pragma unroll
            for (int ks = 0; ks < 2; ++ks) {
                short8v v = {};
                if (val) v = *reinterpret_cast<const short8v*>(kp + ks * 32);
                kb[ks][nf] = v;
            }
        }

        f32x4 accS[4][4] = {};
#pragma unroll
        for (int mf = 0; mf < 4; ++mf)
#pragma unroll
            for (int nf = 0; nf < 4; ++nf) {
                accS[mf][nf] = __builtin_amdgcn_mfma_f32_16x16x32_bf16(qa[0][mf], kb[0][nf], accS[mf][nf], 0, 0, 0);
                accS[mf][nf] = __builtin_amdgcn_mfma_f32_16x16x32_bf16(qa[1][mf], kb[1][nf], accS[mf][nf], 0, 0, 0);
            }

#pragma unroll
        for (int mf = 0; mf < 4; ++mf)
#pragma unroll
            for (int r = 0; r < 4; ++r) {
                int a = mf * 16 + kgrp * 4 + r;
                float s[4];
                float mt = -1e30f;
#pragma unroll
                for (int nf = 0; nf < 4; ++nf) {
                    int n = n0 + nf * 16 + acol;
                    float sv = -1e30f;
                    if (n < NPOS) {
                        sv = accS[mf][nf][r];
                        if (a < AGENT) sv += bf2f(pbh[(size_t)a * NPOS + n]);
                    }
                    s[nf] = sv;
                    mt = fmaxf(mt, sv);
                }
#pragma unroll
                for (int off = 1; off < 16; off <<= 1)
                    mt = fmaxf(mt, __shfl_xor(mt, off));
                float mnew = fmaxf(mrun[mf * 4 + r], mt);
                float fac = __expf(mrun[mf * 4 + r] - mnew);
                float ps = 0.f;
#pragma unroll
                for (int nf = 0; nf < 4; ++nf) {
                    float pv = (s[nf] > -1e29f) ? __expf(s[nf] - mnew) : 0.f;
                    ps += pv;
                    pL[wave][a][nf * 16 + acol] = (short)f2bf(pv);
                }
#pragma unroll
                for (int off = 1; off < 16; off <<= 1)
                    ps += __shfl_xor(ps, off);
                mrun[mf * 4 + r] = mnew;
                lrun[mf * 4 + r] = lrun[mf * 4 + r] * fac + ps;
#pragma unroll
                for (int df = 0; df < 4; ++df) accO[mf][df][r] *= fac;
            }

        short8v vb2[2][4];
#pragma unroll
        for (int ks = 0; ks < 2; ++ks)
#pragma unroll
            for (int df = 0; df < 4; ++df)
                vb2[ks][df] = *reinterpret_cast<const short8v*>(
                    &VtL[wave][df * 16 + acol][ks * 32 + kgrp * 8]);
#pragma unroll
        for (int mf = 0; mf < 4; ++mf) {
#pragma unroll
            for (int ks = 0; ks < 2; ++ks) {
                short8v pa = *reinterpret_cast<const short8v*>(
                    &pL[wave][mf * 16 + acol][ks * 32 + kgrp * 8]);
#pragma unroll
                for (int df = 0; df < 4; ++df)
                    accO[mf][df] = __builtin_amdgcn_mfma_f32_16x16x32_bf16(pa, vb2[ks][df], accO[mf][df], 0, 0, 0);
            }
        }
    }

    if (acol == 0) {
#pragma unroll
        for (int mf = 0; mf < 4; ++mf)
#pragma unroll
            for (int r = 0; r < 4; ++r) {
                mw[wave][mf * 16 + kgrp * 4 + r] = mrun[mf * 4 + r];
                lw[wave][mf * 16 + kgrp * 4 + r] = lrun[mf * 4 + r];
            }
    }
    __syncthreads();
#pragma unroll
    for (int mf = 0; mf < 4; ++mf)
#pragma unroll
        for (int df = 0; df < 4; ++df)
#pragma unroll
            for (int r = 0; r < 4; ++r)
                Om[wave][mf * 16 + kgrp * 4 + r][df * 16 + acol] = accO[mf][df][r];
    __syncthreads();

    for (int idx = tid; idx < AGENT * HD; idx += 256) {
        int a = idx >> 6, d = idx & 63;
        float m = fmaxf(fmaxf(mw[0][a], mw[1][a]), fmaxf(mw[2][a], mw[3][a]));
        float l = 0.f, o = 0.f;
#pragma unroll
        for (int w = 0; w < 4; ++w) {
            float f = __expf(mw[w][a] - m);
            l += f * lw[w][a];
            o += f * Om[w][a][d];
        }
        ((short*)agent_v)[(((size_t)b * HEADS + h) * AGENT + a) * HD + d] = (short)f2bf(o / l);
    }
}

// ---------------------------------------------------------------------------
// Q attention via MFMA (conv split out), in-place over q.
// ---------------------------------------------------------------------------
__global__ __launch_bounds__(256, 4) void q_attn_mfma(
    bf16* qpre0, const float* __restrict__ ahp_x0, const bf16* __restrict__ ab_x0,
    const bf16* __restrict__ agv_x0,
    bf16* qpre1, const float* __restrict__ ahp_x1, const bf16* __restrict__ ab_x1,
    const bf16* __restrict__ agv_x1)
{
    __shared__ short pL[4][16][72];
    __shared__ float oL[4][16][68];

    int sel = blockIdx.x >= BATCH * HEADS * 2;
    int blk = blockIdx.x - sel * BATCH * HEADS * 2;
    bf16* qpre = sel ? qpre1 : qpre0;
    const float* ahp_x = sel ? ahp_x1 : ahp_x0;
    const bf16* ab_x = sel ? ab_x1 : ab_x0;
    const bf16* agv_x = sel ? agv_x1 : agv_x0;

    int half = blk & 1;
    int h = (blk >> 1) % HEADS;
    int b = blk / (2 * HEADS);
    int tid = threadIdx.x;
    int wave = tid >> 6, lane = tid & 63;
    int acol = lane & 15, kgrp = lane >> 4;

    for (int i = tid; i < 4 * 16 * 72; i += 256)
        ((short*)pL)[i] = 0;

    short8v bs[2][4];
#pragma unroll
    for (int ks = 0; ks < 2; ++ks)
#pragma unroll
        for (int nf = 0; nf < 4; ++nf) {
            int a = nf * 16 + acol;
            short8v v = {};
            if (a < AGENT) {
                const float* src = ahp_x + ((size_t)b * AGENT + a) * DIM + h * HD + ks * 32 + kgrp * 8;
                float4 r0 = *reinterpret_cast<const float4*>(src);
                float4 r1 = *reinterpret_cast<const float4*>(src + 4);
                v[0] = (short)f2bf(r0.x * SCALE); v[1] = (short)f2bf(r0.y * SCALE);
                v[2] = (short)f2bf(r0.z * SCALE); v[3] = (short)f2bf(r0.w * SCALE);
                v[4] = (short)f2bf(r1.x * SCALE); v[5] = (short)f2bf(r1.y * SCALE);
                v[6] = (short)f2bf(r1.z * SCALE); v[7] = (short)f2bf(r1.w * SCALE);
            }
            bs[ks][nf] = v;
        }

    const short* agvs = (const short*)agv_x;
    short8v bv[2][4];
#pragma unroll
    for (int ks = 0; ks < 2; ++ks)
#pragma unroll
        for (int nf = 0; nf < 4; ++nf) {
            int d = nf * 16 + acol;
            short8v v = {};
#pragma unroll
            for (int i = 0; i < 8; ++i) {
                int a = ks * 32 + kgrp * 8 + i;
                if (a < AGENT)
                    v[i] = agvs[(((size_t)b * HEADS + h) * AGENT + a) * HD + d];
            }
            bv[ks][nf] = v;
        }

    __syncthreads();

    int tstart = half ? 25 : 0, tend = half ? 49 : 25;
    for (int t = tstart + wave; t < tend; t += 4) {
        int n0 = t * 16;
        const short* qrow = (const short*)qpre +
            ((size_t)(b * NPOS + n0 + acol)) * DIM + h * HD + kgrp * 8;
        short8v a0 = *reinterpret_cast<const short8v*>(qrow);
        short8v a1 = *reinterpret_cast<const short8v*>(qrow + 32);

        f32x4 accs[4] = {};
#pragma unroll
        for (int nf = 0; nf < 4; ++nf) {
            accs[nf] = __builtin_amdgcn_mfma_f32_16x16x32_bf16(a0, bs[0][nf], accs[nf], 0, 0, 0);
            accs[nf] = __builtin_amdgcn_mfma_f32_16x16x32_bf16(a1, bs[1][nf], accs[nf], 0, 0, 0);
        }

        float inv[4];
#pragma unroll
        for (int r = 0; r < 4; ++r) {
            int n = n0 + kgrp * 4 + r;
            float sarr[4];
            float m = -1e30f;
#pragma unroll
            for (int nf = 0; nf < 4; ++nf) {
                int a = nf * 16 + acol;
                float s = -1e30f;
                if (a < AGENT)
                    s = accs[nf][r] + bf2f(ab_x[((size_t)h * NPOS + n) * AGENT + a]);
                sarr[nf] = s;
                m = fmaxf(m, s);
            }
#pragma unroll
            for (int off = 1; off < 16; off <<= 1)
                m = fmaxf(m, __shfl_xor(m, off));
            float ls = 0.f;
#pragma unroll
            for (int nf = 0; nf < 4; ++nf) {
                float p = (sarr[nf] > -1e29f) ? __expf(sarr[nf] - m) : 0.f;
                sarr[nf] = p;
                ls += p;
            }
#pragma unroll
            for (int off = 1; off < 16; off <<= 1)
                ls += __shfl_xor(ls, off);
            inv[r] = 1.f / ls;
#pragma unroll
            for (int nf = 0; nf < 4; ++nf) {
                int a = nf * 16 + acol;
                if (a < AGENT)
                    pL[wave][kgrp * 4 + r][a] = (short)f2bf(sarr[nf]);
            }
        }

        short8v p0 = *reinterpret_cast<const short8v*>(&pL[wave][acol][kgrp * 8]);
        short8v p1 = *reinterpret_cast<const short8v*>(&pL[wave][acol][kgrp * 8 + 32]);

        f32x4 acco[4] = {};
#pragma unroll
        for (int nf = 0; nf < 4; ++nf) {
            acco[nf] = __builtin_amdgcn_mfma_f32_16x16x32_bf16(p0, bv[0][nf], acco[nf], 0, 0, 0);
            acco[nf] = __builtin_amdgcn_mfma_f32_16x16x32_bf16(p1, bv[1][nf], acco[nf], 0, 0, 0);
        }

#pragma unroll
        for (int r = 0; r < 4; ++r)
#pragma unroll
            for (int nf = 0; nf < 4; ++nf)
                oL[wave][kgrp * 4 + r][nf * 16 + acol] = acco[nf][r] * inv[r];

#pragma unroll
        for (int it2 = 0; it2 < 2; ++it2) {
            int item = lane + 64 * it2;
            int rl = item >> 3, d8 = item & 7;
            int n = n0 + rl;
            float4 o0 = *reinterpret_cast<const float4*>(&oL[wave][rl][d8 * 8]);
            float4 o1 = *reinterpret_cast<const float4*>(&oL[wave][rl][d8 * 8 + 4]);
            short8v ov;
            ov[0] = (short)f2bf(o0.x); ov[1] = (short)f2bf(o0.y);
            ov[2] = (short)f2bf(o0.z); ov[3] = (short)f2bf(o0.w);
            ov[4] = (short)f2bf(o1.x); ov[5] = (short)f2bf(o1.y);
            ov[6] = (short)f2bf(o1.z); ov[7] = (short)f2bf(o1.w);
            *reinterpret_cast<short8v*>((short*)qpre +
                ((size_t)(b * NPOS + n)) * DIM + h * HD + d8 * 8) = ov;
        }
    }
}

// ---------------------------------------------------------------------------
// Depthwise 3x3 conv, LDS-tiled: pre += conv(V) + bias. Both modalities.
// ---------------------------------------------------------------------------
__global__ __launch_bounds__(256, 3) void dwc_kernel(
    bf16* pre0, const bf16* __restrict__ kv0,
    const float* __restrict__ w0, const float* __restrict__ b0,
    bf16* pre1, const bf16* __restrict__ kv1,
    const float* __restrict__ w1, const float* __restrict__ b1)
{
    __shared__ __align__(16) short Vs[168][136];
    __shared__ float wS[9][128];
    __shared__ float cbS[128];

    int blk = blockIdx.x;
    int per = BATCH * CONV_CG * CONV_IG;
    int sel = blk >= per;
    blk -= sel * per;
    bf16* pre = sel ? pre1 : pre0;
    const short* kvs = (const short*)(sel ? kv1 : kv0);
    const float* dw = sel ? w1 : w0;
    const float* db = sel ? b1 : b0;

    int ig = blk % CONV_IG;
    int cg = (blk / CONV_IG) % CONV_CG;
    int b  = blk / (CONV_IG * CONV_CG);
    int c0 = cg * 128;
    int tid = threadIdx.x;

    for (int i = tid; i < 9 * 128; i += 256)
        wS[i >> 7][i & 127] = dw[(i >> 7) * DIM + c0 + (i & 127)];
    if (tid < 128) cbS[tid] = db[c0 + tid];

    for (int it = 0; it < 11; ++it) {
        int item = tid + 256 * it;
        if (item >= 168 * 16) break;
        int pos = item >> 4, c8 = item & 15;
        int ii = pos / 28, jj = pos % 28;
        int irow = ig * 4 - 1 + ii;
        short8v v = {};
        if (irow >= 0 && irow < HH)
            v = *reinterpret_cast<const short8v*>(
                kvs + (size_t)(b * NPOS + irow * WW + jj) * (2 * DIM) + DIM + c0 + c8 * 8);
        *reinterpret_cast<short8v*>(&Vs[pos][c8 * 8]) = v;
    }
    __syncthreads();

#pragma unroll
    for (int it = 0; it < 7; ++it) {
        int item = tid + 256 * it;
        int opos = item >> 4, c8 = item & 15;
        int oi = opos / 28, oj = opos % 28;
        int n = (ig * 4 + oi) * WW + oj;
        short* pp = (short*)pre + (size_t)(b * NPOS + n) * DIM + c0 + c8 * 8;
        short8v pv = *reinterpret_cast<const short8v*>(pp);
        float acc[8];
#pragma unroll
        for (int u = 0; u < 8; ++u) acc[u] = bfs2f(pv[u]) + cbS[c8 * 8 + u];
#pragma unroll
        for (int di = -1; di <= 1; ++di) {
#pragma unroll
            for (int dj = -1; dj <= 1; ++dj) {
                int jj = oj + dj;
                if (jj < 0 || jj >= WW) continue;
                int pos = (oi + 1 + di) * 28 + jj;
                short8v vv = *reinterpret_cast<const short8v*>(&Vs[pos][c8 * 8]);
                int tap = (di + 1) * 3 + (dj + 1);
#pragma unroll
                for (int u = 0; u < 8; ++u)
                    acc[u] += wS[tap][c8 * 8 + u] * bfs2f(vv[u]);
            }
        }
        short8v ov;
#pragma unroll
        for (int u = 0; u < 8; ++u) ov[u] = (short)f2bf(acc[u]);
        *reinterpret_cast<short8v*>(pp) = ov;
    }
}

// ---------------------------------------------------------------------------
extern "C" void kernel_launch(void* const* d_in, const int* in_sizes, int n_in,
                              void* d_out, int out_size, void* d_ws, size_t ws_size,
                              hipStream_t stream)
{
    const float* rgb_fea    = (const float*)d_in[0];
    const float* depth_fea  = (const float*)d_in[1];
    const float* rgb_q_w    = (const float*)d_in[2];
    const float* rgb_kv_w   = (const float*)d_in[3];
    const float* rgb_proj_w = (const float*)d_in[4];
    const float* rgb_proj_b = (const float*)d_in[5];
    const float* depth_q_w    = (const float*)d_in[6];
    const float* depth_kv_w   = (const float*)d_in[7];
    const float* depth_proj_w = (const float*)d_in[8];
    const float* depth_proj_b = (const float*)d_in[9];
    const float* rgb_dwc_w   = (const float*)d_in[10];
    const float* rgb_dwc_b   = (const float*)d_in[11];
    const float* depth_dwc_w = (const float*)d_in[12];
    const float* depth_dwc_b = (const float*)d_in[13];
    const float* rgb_an   = (const float*)d_in[14];
    const float* rgb_na   = (const float*)d_in[15];
    const float* rgb_ah_b = (const float*)d_in[16];
    const float* rgb_aw_b = (const float*)d_in[17];
    const float* rgb_ha_b = (const float*)d_in[18];
    const float* rgb_wa_b = (const float*)d_in[19];
    const float* depth_an   = (const float*)d_in[20];
    const float* depth_na   = (const float*)d_in[21];
    const float* depth_ah_b = (const float*)d_in[22];
    const float* depth_aw_b = (const float*)d_in[23];
    const float* depth_ha_b = (const float*)d_in[24];
    const float* depth_wa_b = (const float*)d_in[25];

    char* ws = (char*)d_ws;
    size_t off = 0;
    auto alloc = [&](size_t bytes) -> void* {
        void* p = ws + off;
        off += (bytes + 255) & ~(size_t)255;
        return p;
    };
    bf16* rgb_q    = (bf16*)alloc((size_t)MROWS * DIM * 2);
    bf16* depth_q  = (bf16*)alloc((size_t)MROWS * DIM * 2);
    bf16* rgb_kv   = (bf16*)alloc((size_t)MROWS * 2 * DIM * 2);
    bf16* depth_kv = (bf16*)alloc((size_t)MROWS * 2 * DIM * 2);
    bf16* rgb_pb    = (bf16*)alloc((size_t)HEADS * AGENT * NPOS * 2);
    bf16* depth_pb  = (bf16*)alloc((size_t)HEADS * AGENT * NPOS * 2);
    bf16* rgb_ab    = (bf16*)alloc((size_t)HEADS * NPOS * AGENT * 2);
    bf16* depth_ab  = (bf16*)alloc((size_t)HEADS * NPOS * AGENT * 2);
    bf16* rgb_agv   = (bf16*)alloc((size_t)BATCH * HEADS * AGENT * HD * 2);
    bf16* depth_agv = (bf16*)alloc((size_t)BATCH * HEADS * AGENT * HD * 2);
    bf16* proj_wt_r = (bf16*)alloc((size_t)DIM * DIM * 2);
    bf16* proj_wt_d = (bf16*)alloc((size_t)DIM * DIM * 2);
    size_t ubase = off;
    bf16* comb_wt_r = (bf16*)alloc((size_t)3 * DIM * DIM * 2);
    bf16* comb_wt_d = (bf16*)alloc((size_t)3 * DIM * DIM * 2);
    off = ubase;  // alias (weights dead before ahp written)
    float* rgb_ahp   = (float*)alloc((size_t)BATCH * AGENT * DIM * 4);
    float* depth_ahp = (float*)alloc((size_t)BATCH * AGENT * DIM * 4);

    // d_out doubles as scratch for the bf16-converted activations
    bf16* fea_bf_r = (bf16*)d_out;
    bf16* fea_bf_d = fea_bf_r + (size_t)MROWS * DIM;

    dim3 blk(256);

    // 0) prologue megakernel: convert + 3 transposes + 2 bias kernels
    prologue_kernel<<<NB_PROLOGUE, blk, 0, stream>>>(
        rgb_fea, fea_bf_r, depth_fea, fea_bf_d,
        rgb_q_w, depth_q_w, rgb_kv_w, depth_kv_w, rgb_proj_w, depth_proj_w,
        comb_wt_r, comb_wt_d, proj_wt_r, proj_wt_d,
        rgb_an, rgb_ah_b, rgb_aw_b, rgb_pb,
        depth_an, depth_ah_b, depth_aw_b, depth_pb,
        rgb_na, rgb_ha_b, rgb_wa_b, rgb_ab,
        depth_na, depth_ha_b, depth_wa_b, depth_ab);

    // 1) q+kv projections fused (col-split routing)
    gemm_mfma<false><<<dim3(18, 392), blk, 0, stream>>>(
        fea_bf_r, comb_wt_r, nullptr, rgb_q, rgb_kv,
        fea_bf_d, comb_wt_d, nullptr, depth_q, depth_kv,
        MROWS, 3 * DIM, DIM, DIM);

    // 2) agent pooling (merged)
    pool_kernel_2<<<(2 * BATCH * AGENT * DIM + 255) / 256, blk, 0, stream>>>(
        rgb_q, rgb_ahp, depth_q, depth_ahp);

    // 3) cross-modal agent aggregation (both modalities, one dispatch)
    agent_attn3<<<2 * BATCH * HEADS, blk, 0, stream>>>(
        depth_ahp, rgb_kv, rgb_pb, depth_agv,
        rgb_ahp, depth_kv, depth_pb, rgb_agv);

    // 4) agent broadcast (in-place q -> attention output)
    q_attn_mfma<<<2 * BATCH * HEADS * 2, blk, 0, stream>>>(
        rgb_q, depth_ahp, depth_ab, depth_agv,
        depth_q, rgb_ahp, rgb_ab, rgb_agv);

    // 5) depthwise conv added in (LDS-tiled, both modalities)
    dwc_kernel<<<2 * BATCH * CONV_CG * CONV_IG, blk, 0, stream>>>(
        rgb_q, rgb_kv, rgb_dwc_w, rgb_dwc_b,
        depth_q, depth_kv, depth_dwc_w, depth_dwc_b);

    // 6) output projections (merged; overwrite d_out scratch with results)
    float* out = (float*)d_out;
    gemm_mfma<true><<<dim3(6, 392), blk, 0, stream>>>(
        rgb_q, proj_wt_r, rgb_proj_b, out, nullptr,
        depth_q, proj_wt_d, depth_proj_b, out + (size_t)MROWS * DIM, nullptr,
        MROWS, DIM, DIM, 0);
}